// Round 4
// baseline (259.646 us; speedup 1.0000x reference)
//
#include <hip/hip_runtime.h>
#include <hip/hip_bf16.h>

typedef __hip_bfloat16 bf16;
typedef short bf16x8 __attribute__((ext_vector_type(8)));
typedef float f32x4 __attribute__((ext_vector_type(4)));
typedef float f32x2 __attribute__((ext_vector_type(2)));
typedef _Float16 f16x2 __attribute__((ext_vector_type(2)));
typedef _Float16 f16x8 __attribute__((ext_vector_type(8)));
typedef __fp16 fp16x2 __attribute__((ext_vector_type(2)));   // cvt_pkrtz result type

#define N_NODES  10000
#define G_GRAPHS 200
#define EL_EDGES 160000
#define EG_EDGES 500000
#define S_DIM    256
#define APAD     264   // k_node LDS row stride in bf16

#define BONDS2        7813    // ceil(500000 / 64): 1 wave = 16 edges, 4 waves/block
#define LOCAL_BLOCKS  625     // 160000 / 256 exact

// ---------------- workspace layout (float offsets) ----------------
#define WS_FLAG   0         // input dtype flag (0=bf16, 1=f32)
#define WS_POSC   1024      // 30000: centered positions f32
#define WS_WD     31232     // 256 f32: wd PERMUTED to storage order
#define WS_W1F    31488     // 4096 f16 (2048 slots): W_b1 B-fragments, CHAN-mapped
#define WS_BB0R   33536     // 256: b_b0 original order (h-fold)
#define WS_BB1    34304     // 16   b_b1 (10, padded)
#define WS_WATOM  34560     // 4096 W_atom (16x256) f32
#define WS_WTIME  38656     // 256
#define WS_BTIME  38912     // 256
#define WS_BATOM  39168     // 256
#define WS_BAT    39424     // 256
#define WS_BSH    39680     // 256
#define WS_BATOMS 39936     // 32
#define WS_T      40000     // 200
#define WS_X      40448     // 160000 (N x 16) f32
#define WT_AT     200448    // 65536 bf16: W_at^T [n][k]
#define WT_SH     233216    // 65536 bf16: W_shared^T [n][k]
#define WT_B0     265984    // 65536 bf16: W_b0[:256]^T [n][k]
#define WT_ATOMS  298752    // 8192 bf16: W_atoms^T [n][k]
#define WS_H      303968    // N*256 fp8 bytes = 640,000 float slots
#define WS_END_FLOATS 944224   // ~3.78 MB

// fp8-h storage permutation: storage byte index S -> original channel.
// k_node packs dword (wave*16+l16) with channels n0+l16+{0,16,32,48}.
#define CHAN(S)    ((((S) >> 6) << 6) + (((S) & 3) << 4) + (((S) & 63) >> 2))

// ---------------- output layout (element offsets) ----------------
#define O_CPRED 0        // (N,3)
#define O_CEPS  30000    // (N,3)
#define O_APRED 60000    // (N,16)
#define O_AEPS  220000   // (N,16)
#define O_BPRED 380000   // (EG,5)
#define O_BEPS  2880000  // (EG,5)
#define O_DL    5380000  // (EL,)
#define O_RNL   5540000  // (EL,3)
#define O_AG    6020000  // (EG,)
#define O_RNG   6520000  // (EG,3)

__device__ __forceinline__ float b2f(bf16 v) { return __bfloat162float(v); }
__device__ __forceinline__ bf16  f2b(float v) { return __float2bfloat16(v); }
__device__ __forceinline__ unsigned short bbits(float v) {
    bf16 b = f2b(v);
    return *reinterpret_cast<unsigned short*>(&b);
}
__device__ __forceinline__ unsigned short h16bits(float v) {
    _Float16 h = (_Float16)v;
    return *reinterpret_cast<unsigned short*>(&h);
}
__device__ __forceinline__ float ldin(const void* p, int idx, int isf32) {
    return isf32 ? ((const float*)p)[idx] : b2f(((const bf16*)p)[idx]);
}
__device__ __forceinline__ void stout(void* out, int f32o, size_t idx, float v) {
    if (f32o) ((float*)out)[idx] = v;
    else      ((bf16*)out)[idx]  = f2b(v);
}
__device__ __forceinline__ float silu(float p) {
    return p * __builtin_amdgcn_rcpf(1.0f + __expf(-p));
}
__device__ __forceinline__ f32x2 silu2(f32x2 p) {
    f32x2 u;
    u[0] = p[0] * __builtin_amdgcn_rcpf(1.0f + __expf(-p[0]));
    u[1] = p[1] * __builtin_amdgcn_rcpf(1.0f + __expf(-p[1]));
    return u;
}
// dtype sniff: t ~ U(0,1). bf16 halfwords all < 0x4000.
__device__ __forceinline__ int dtype_f32(const void* tt) {
    const unsigned short* q = (const unsigned short*)tt;
    int c = 0;
#pragma unroll
    for (int z = 0; z < 32; ++z) c += (q[z] >= 0x4000) ? 1 : 0;
    return c > 0;
}

// ---------------- canonicalize inputs; build transposed weights ----------
__global__ void k_prep(const void* __restrict__ x, const void* __restrict__ tt,
                       const void* __restrict__ W_time, const void* __restrict__ b_time,
                       const void* __restrict__ W_atom, const void* __restrict__ b_atom,
                       const void* __restrict__ W_at, const void* __restrict__ b_at,
                       const void* __restrict__ W_shared, const void* __restrict__ b_shared,
                       const void* __restrict__ W_b0, const void* __restrict__ b_b0,
                       const void* __restrict__ W_b1, const void* __restrict__ b_b1,
                       const void* __restrict__ W_atoms, const void* __restrict__ b_atoms,
                       float* __restrict__ ws) {
    const int t = blockIdx.x * blockDim.x + threadIdx.x;  // 640*256 = 163840
    const int f = dtype_f32(tt);
    if (t == 0) ws[WS_FLAG] = f ? 1.0f : 0.0f;
    if (t < 65536) {
        const int k = t >> 8, n = t & 255;
        ((unsigned short*)(ws + WT_AT))[n * 256 + k] = bbits(ldin(W_at, t, f));
        ((unsigned short*)(ws + WT_SH))[n * 256 + k] = bbits(ldin(W_shared, t, f));
        ((unsigned short*)(ws + WT_B0))[n * 256 + k] = bbits(ldin(W_b0, t, f));
    }
    if (t < 160000) ws[WS_X + t] = ldin(x, t, f);
    if (t < 8192) {
        const int k = t >> 5, n = t & 31;   // W_atoms (256,32)
        ((unsigned short*)(ws + WT_ATOMS))[n * 256 + k] = bbits(ldin(W_atoms, t, f));
    }
    if (t < 4096) {
        // W_b1 f16 B-fragments, CHAN-mapped: t = ts*512 + quad*128 + l16*8 + i
        const int i = t & 7, lc = (t >> 3) & 15, q = (t >> 7) & 3, ts = t >> 9;
        const int s = ts * 32 + q * 8 + i;          // storage channel
        float v = (lc < 10) ? ldin(W_b1, CHAN(s) * 10 + lc, f) : 0.0f;
        ((unsigned short*)(ws + WS_W1F))[t] = h16bits(v);
    }
    if (t < 4096) ws[WS_WATOM + t] = ldin(W_atom, t, f);
    if (t < 256) {
        ws[WS_WD + t]   = ldin(W_b0, 65536 + CHAN(t), f);  // permuted wd (f32)
        ws[WS_BB0R + t] = ldin(b_b0, t, f);                // ORIGINAL order
        ws[WS_WTIME + t] = ldin(W_time, t, f);
        ws[WS_BTIME + t] = ldin(b_time, t, f);
        ws[WS_BATOM + t] = ldin(b_atom, t, f);
        ws[WS_BAT + t]   = ldin(b_at, t, f);
        ws[WS_BSH + t]   = ldin(b_shared, t, f);
    }
    if (t < 200) ws[WS_T + t] = ldin(tt, t, f);
    if (t < 32)  ws[WS_BATOMS + t] = ldin(b_atoms, t, f);
    if (t < 16)  ws[WS_BB1 + t] = (t < 10) ? ldin(b_b1, t, f) : 0.0f;
}

// ---------------- per-graph mean + center (sorted batch) -----------------
__global__ void k_pos(const void* __restrict__ pos, const int* __restrict__ batch,
                      float* __restrict__ ws, void* __restrict__ out) {
    const int g = blockIdx.x;
    const int f32o = ws[WS_FLAG] != 0.0f;
    __shared__ int s_lo, s_hi;
    __shared__ float wsum[4][3];
    __shared__ float mean[3];
    if (threadIdx.x == 0) {
        int lo = 0, hi = N_NODES;
        while (lo < hi) { int m = (lo + hi) >> 1; if (batch[m] < g) lo = m + 1; else hi = m; }
        s_lo = lo;
        int lo2 = lo; hi = N_NODES;
        while (lo2 < hi) { int m = (lo2 + hi) >> 1; if (batch[m] < g + 1) lo2 = m + 1; else hi = m; }
        s_hi = lo2;
    }
    __syncthreads();
    const int lo = s_lo, hi = s_hi, cnt = hi - lo;
    float sx = 0.f, sy = 0.f, sz = 0.f;
    for (int n = lo + threadIdx.x; n < hi; n += 256) {
        sx += ldin(pos, n * 3 + 0, f32o);
        sy += ldin(pos, n * 3 + 1, f32o);
        sz += ldin(pos, n * 3 + 2, f32o);
    }
#pragma unroll
    for (int off = 32; off > 0; off >>= 1) {
        sx += __shfl_down(sx, off);
        sy += __shfl_down(sy, off);
        sz += __shfl_down(sz, off);
    }
    if ((threadIdx.x & 63) == 0) {
        wsum[threadIdx.x >> 6][0] = sx;
        wsum[threadIdx.x >> 6][1] = sy;
        wsum[threadIdx.x >> 6][2] = sz;
    }
    __syncthreads();
    if (threadIdx.x == 0) {
        float inv = 1.0f / (float)max(cnt, 1);
        mean[0] = (wsum[0][0] + wsum[1][0] + wsum[2][0] + wsum[3][0]) * inv;
        mean[1] = (wsum[0][1] + wsum[1][1] + wsum[2][1] + wsum[3][1]) * inv;
        mean[2] = (wsum[0][2] + wsum[1][2] + wsum[2][2] + wsum[3][2]) * inv;
    }
    __syncthreads();
    for (int n = lo + threadIdx.x; n < hi; n += 256) {
#pragma unroll
        for (int k = 0; k < 3; ++k) {
            float p = ldin(pos, n * 3 + k, f32o) - mean[k];
            ws[WS_POSC + n * 3 + k] = p;
            stout(out, f32o, O_CPRED + n * 3 + k, p);
            stout(out, f32o, O_CEPS + n * 3 + k, 0.0f);
        }
    }
}

// ---------------- MFMA node pipeline: 16 rows/block, 4 waves -------------
__global__ __launch_bounds__(256) void k_node(
    const int* __restrict__ batch, const float* __restrict__ ws,
    unsigned int* __restrict__ h_out, void* __restrict__ out) {
    __shared__ unsigned short actA[16][APAD];
    __shared__ unsigned short actB[16][APAD];
    const int tid = threadIdx.x;
    const int wave = tid >> 6, lane = tid & 63;
    const int quad = lane >> 4, l16 = lane & 15;
    const int row0 = blockIdx.x * 16;

    // ---- stage 0 (VALU f32): s0 = x@W_atom + b_atom + t[batch]*W_time + b_time
    {
        const int r = tid >> 4;
        const int c0 = (tid & 15) * 16;
        const int g = row0 + r;
        float tb = ws[WS_T + batch[g]];
        float xr[16];
#pragma unroll
        for (int k = 0; k < 16; ++k) xr[k] = ws[WS_X + g * 16 + k];
        for (int cc = 0; cc < 16; cc += 4) {
            const int c = c0 + cc;
            float a0 = ws[WS_BATOM + c + 0] + tb * ws[WS_WTIME + c + 0] + ws[WS_BTIME + c + 0];
            float a1 = ws[WS_BATOM + c + 1] + tb * ws[WS_WTIME + c + 1] + ws[WS_BTIME + c + 1];
            float a2 = ws[WS_BATOM + c + 2] + tb * ws[WS_WTIME + c + 2] + ws[WS_BTIME + c + 2];
            float a3 = ws[WS_BATOM + c + 3] + tb * ws[WS_WTIME + c + 3] + ws[WS_BTIME + c + 3];
#pragma unroll
            for (int k = 0; k < 16; ++k) {
                float4 w4 = *(const float4*)(ws + WS_WATOM + k * S_DIM + c);
                a0 += xr[k] * w4.x; a1 += xr[k] * w4.y;
                a2 += xr[k] * w4.z; a3 += xr[k] * w4.w;
            }
            actA[r][c + 0] = bbits(a0); actA[r][c + 1] = bbits(a1);
            actA[r][c + 2] = bbits(a2); actA[r][c + 3] = bbits(a3);
        }
    }
    __syncthreads();

    const unsigned short* wt_at = (const unsigned short*)(ws + WT_AT);
    const unsigned short* wt_sh = (const unsigned short*)(ws + WT_SH);
    const unsigned short* wt_b0 = (const unsigned short*)(ws + WT_B0);
    const unsigned short* wt_am = (const unsigned short*)(ws + WT_ATOMS);
    const int n0 = wave * 64;

    // ---- layer 1: actB = actA @ W_at + b_at
    {
        f32x4 acc[4] = {};
        for (int kk = 0; kk < S_DIM; kk += 32) {
            const int k = kk + quad * 8;
            bf16x8 a = *(const bf16x8*)&actA[l16][k];
#pragma unroll
            for (int nt = 0; nt < 4; ++nt) {
                bf16x8 b = *(const bf16x8*)(wt_at + (size_t)(n0 + nt * 16 + l16) * S_DIM + k);
                acc[nt] = __builtin_amdgcn_mfma_f32_16x16x32_bf16(a, b, acc[nt], 0, 0, 0);
            }
        }
#pragma unroll
        for (int nt = 0; nt < 4; ++nt) {
            const int n = n0 + nt * 16 + l16;
            const float bv = ws[WS_BAT + n];
#pragma unroll
            for (int r = 0; r < 4; ++r)
                actB[quad * 4 + r][n] = bbits(acc[nt][r] + bv);
        }
    }
    __syncthreads();

    // ---- layer 2: actA = silu(actB @ W_shared + b_shared)
    {
        f32x4 acc[4] = {};
        for (int kk = 0; kk < S_DIM; kk += 32) {
            const int k = kk + quad * 8;
            bf16x8 a = *(const bf16x8*)&actB[l16][k];
#pragma unroll
            for (int nt = 0; nt < 4; ++nt) {
                bf16x8 b = *(const bf16x8*)(wt_sh + (size_t)(n0 + nt * 16 + l16) * S_DIM + k);
                acc[nt] = __builtin_amdgcn_mfma_f32_16x16x32_bf16(a, b, acc[nt], 0, 0, 0);
            }
        }
        __syncthreads();
#pragma unroll
        for (int nt = 0; nt < 4; ++nt) {
            const int n = n0 + nt * 16 + l16;
            const float bv = ws[WS_BSH + n];
#pragma unroll
            for (int r = 0; r < 4; ++r)
                actA[quad * 4 + r][n] = bbits(silu(acc[nt][r] + bv));
        }
    }
    __syncthreads();

    // ---- layer 3: h = actA @ W_b0[:256] + 0.5*b_b0, fp8 e4m3 PERMUTED pack
    {
        f32x4 acc[4] = {};
        for (int kk = 0; kk < S_DIM; kk += 32) {
            const int k = kk + quad * 8;
            bf16x8 a = *(const bf16x8*)&actA[l16][k];
#pragma unroll
            for (int nt = 0; nt < 4; ++nt) {
                bf16x8 b = *(const bf16x8*)(wt_b0 + (size_t)(n0 + nt * 16 + l16) * S_DIM + k);
                acc[nt] = __builtin_amdgcn_mfma_f32_16x16x32_bf16(a, b, acc[nt], 0, 0, 0);
            }
        }
        float bh[4];
#pragma unroll
        for (int nt = 0; nt < 4; ++nt) bh[nt] = 0.5f * ws[WS_BB0R + n0 + nt * 16 + l16];
#pragma unroll
        for (int r = 0; r < 4; ++r) {
            const int g = row0 + quad * 4 + r;
            int w = 0;
            w = __builtin_amdgcn_cvt_pk_fp8_f32(acc[0][r] + bh[0], acc[1][r] + bh[1], w, false);
            w = __builtin_amdgcn_cvt_pk_fp8_f32(acc[2][r] + bh[2], acc[3][r] + bh[3], w, true);
            h_out[(size_t)g * 64 + wave * 16 + l16] = (unsigned int)w;
        }
    }

    // ---- layer 4: atoms = actA @ W_atoms + b_atoms (256 -> 32), waves 0,1
    if (wave < 2) {
        f32x4 acc = {};
        const int n = wave * 16 + l16;
        for (int kk = 0; kk < S_DIM; kk += 32) {
            const int k = kk + quad * 8;
            bf16x8 a = *(const bf16x8*)&actA[l16][k];
            bf16x8 b = *(const bf16x8*)(wt_am + (size_t)n * S_DIM + k);
            acc = __builtin_amdgcn_mfma_f32_16x16x32_bf16(a, b, acc, 0, 0, 0);
        }
        const float bv = ws[WS_BATOMS + n];
        const int f32o = ws[WS_FLAG] != 0.0f;
#pragma unroll
        for (int r = 0; r < 4; ++r) {
            const int g = row0 + quad * 4 + r;
            float v = acc[r] + bv;
            if (n < 16) stout(out, f32o, O_AEPS + (size_t)g * 16 + n, v);
            else        stout(out, f32o, O_APRED + (size_t)g * 16 + (n - 16), v);
        }
    }
}

// ---------------- fused edges kernel, LDS-free bonds ---------------------
// Blocks [0, BONDS2): global edges. One wave = 16 edges, full K=256 via 8
// f16 MFMAs; h gathered as fp8 (2.56 MB, per-XCD-L2-resident), decoded to
// f32 pairs, p in packed f32, silu f32, u packed to f16 via cvt_pkrtz.
// Blocks [BONDS2, BONDS2+625): local edge attrs, one thread/edge.
union U8 { f16x8 v; fp16x2 p[4]; };

__global__ __launch_bounds__(256, 4) void k_edges(const int* __restrict__ eig,
                                                  const int* __restrict__ eil,
                                                  const float* __restrict__ ws,
                                                  const unsigned char* __restrict__ h,
                                                  void* __restrict__ out) {
    const int f32o = ws[WS_FLAG] != 0.0f;

    if (blockIdx.x >= BONDS2) {
        // ---- local edges: 625 blocks x 256 threads == 160000 exact ----
        const int e = (blockIdx.x - BONDS2) * 256 + threadIdx.x;
        const float* posc = ws + WS_POSC;
        const int s = eil[e];
        const int t = eil[EL_EDGES + e];
        float rx = posc[t * 3 + 0] - posc[s * 3 + 0];
        float ry = posc[t * 3 + 1] - posc[s * 3 + 1];
        float rz = posc[t * 3 + 2] - posc[s * 3 + 2];
        float dsq = rx * rx + ry * ry + rz * rz;
        float d = sqrtf(fmaxf(dsq, 1e-6f));
        float inv = 1.0f / d;
        stout(out, f32o, O_DL + e, d);
        stout(out, f32o, O_RNL + (size_t)e * 3 + 0, rx * inv);
        stout(out, f32o, O_RNL + (size_t)e * 3 + 1, ry * inv);
        stout(out, f32o, O_RNL + (size_t)e * 3 + 2, rz * inv);
        return;
    }

    const int wave = threadIdx.x >> 6, lane = threadIdx.x & 63;
    const int quad = lane >> 4, l16 = lane & 15;
    const int e0 = blockIdx.x * 64 + wave * 16;
    if (e0 >= EG_EDGES) return;          // tail waves of last bonds block

    const int e = e0 + l16;
    const int j = eig[e];                // src
    const int i = eig[EG_EDGES + e];     // tgt

    // ---- geometry (per-lane; quads redundant, broadcast loads) ----
    const float* posc = ws + WS_POSC;
    float pix = posc[i * 3 + 0], piy = posc[i * 3 + 1], piz = posc[i * 3 + 2];
    float pjx = posc[j * 3 + 0], pjy = posc[j * 3 + 1], pjz = posc[j * 3 + 2];
    float rx = pix - pjx, ry = piy - pjy, rz = piz - pjz;
    float dsq = rx * rx + ry * ry + rz * rz;
    float dgeo = sqrtf(dsq);             // bonds d: no clip
    if (quad == 0) {
        float ag = pix * pjx + piy * pjy + piz * pjz;
        float inv = 1.0f / sqrtf(fmaxf(dsq, 1e-6f));
        stout(out, f32o, O_AG + e, ag);
        stout(out, f32o, O_RNG + (size_t)e * 3 + 0, rx * inv);
        stout(out, f32o, O_RNG + (size_t)e * 3 + 1, ry * inv);
        stout(out, f32o, O_RNG + (size_t)e * 3 + 2, rz * inv);
    }

    const f32x2 d2 = {dgeo, dgeo};
    const unsigned char* hi_row = h + (size_t)i * 256;
    const unsigned char* hj_row = h + (size_t)j * 256;
    const _Float16* w1f = (const _Float16*)(ws + WS_W1F) + (quad * 16 + l16) * 8;

    f32x4 acc = {};
#pragma unroll 2
    for (int t = 0; t < 8; ++t) {
        const int k = quad * 8 + t * 32;             // storage channel base
        uint2 ua = *(const uint2*)(hi_row + k);
        uint2 ub = *(const uint2*)(hj_row + k);
        float4 wA = *(const float4*)(ws + WS_WD + k);
        float4 wB = *(const float4*)(ws + WS_WD + k + 4);
        f16x8 WF = *(const f16x8*)(w1f + t * 512);
        f32x2 a01 = __builtin_amdgcn_cvt_pk_f32_fp8((int)ua.x, false);
        f32x2 a23 = __builtin_amdgcn_cvt_pk_f32_fp8((int)ua.x, true);
        f32x2 a45 = __builtin_amdgcn_cvt_pk_f32_fp8((int)ua.y, false);
        f32x2 a67 = __builtin_amdgcn_cvt_pk_f32_fp8((int)ua.y, true);
        f32x2 b01 = __builtin_amdgcn_cvt_pk_f32_fp8((int)ub.x, false);
        f32x2 b23 = __builtin_amdgcn_cvt_pk_f32_fp8((int)ub.x, true);
        f32x2 b45 = __builtin_amdgcn_cvt_pk_f32_fp8((int)ub.y, false);
        f32x2 b67 = __builtin_amdgcn_cvt_pk_f32_fp8((int)ub.y, true);
        f32x2 p01 = (a01 + b01) + d2 * (f32x2){wA.x, wA.y};
        f32x2 p23 = (a23 + b23) + d2 * (f32x2){wA.z, wA.w};
        f32x2 p45 = (a45 + b45) + d2 * (f32x2){wB.x, wB.y};
        f32x2 p67 = (a67 + b67) + d2 * (f32x2){wB.z, wB.w};
        f32x2 u01 = silu2(p01);
        f32x2 u23 = silu2(p23);
        f32x2 u45 = silu2(p45);
        f32x2 u67 = silu2(p67);
        U8 U;
        U.p[0] = __builtin_amdgcn_cvt_pkrtz(u01[0], u01[1]);
        U.p[1] = __builtin_amdgcn_cvt_pkrtz(u23[0], u23[1]);
        U.p[2] = __builtin_amdgcn_cvt_pkrtz(u45[0], u45[1]);
        U.p[3] = __builtin_amdgcn_cvt_pkrtz(u67[0], u67[1]);
        acc = __builtin_amdgcn_mfma_f32_16x16x32_f16(U.v, WF, acc, 0, 0, 0);
    }

    // ---- epilogue: C[row=quad*4+r][col=l16] -> bonds outputs ----
    if (l16 < 10) {
        const float bv = ws[WS_BB1 + l16];
#pragma unroll
        for (int r = 0; r < 4; ++r) {
            const int er = e0 + quad * 4 + r;
            float v = acc[r] + bv;
            if (l16 < 5) stout(out, f32o, O_BPRED + (size_t)er * 5 + l16, v);
            else         stout(out, f32o, O_BEPS + (size_t)er * 5 + (l16 - 5), v);
        }
    }
}

extern "C" void kernel_launch(void* const* d_in, const int* in_sizes, int n_in,
                              void* d_out, int out_size, void* d_ws, size_t ws_size,
                              hipStream_t stream) {
    const void* x        = d_in[0];
    const void* t        = d_in[1];
    const void* pos      = d_in[2];
    const int*  eil      = (const int*)d_in[3];
    const int*  eig      = (const int*)d_in[4];
    const int*  batch    = (const int*)d_in[6];
    const void* W_time   = d_in[7];
    const void* b_time   = d_in[8];
    const void* W_atom   = d_in[9];
    const void* b_atom   = d_in[10];
    const void* W_at     = d_in[11];
    const void* b_at     = d_in[12];
    const void* W_shared = d_in[13];
    const void* b_shared = d_in[14];
    const void* W_b0     = d_in[15];
    const void* b_b0     = d_in[16];
    const void* W_b1     = d_in[17];
    const void* b_b1     = d_in[18];
    const void* W_atoms  = d_in[20];
    const void* b_atoms  = d_in[21];
    (void)in_sizes; (void)n_in; (void)out_size;

    const size_t NEED = (size_t)WS_END_FLOATS * sizeof(float);
    if (ws_size < NEED) return;

    float* ws = (float*)d_ws;
    unsigned int* hbuf = (unsigned int*)(ws + WS_H);

    k_prep<<<640, 256, 0, stream>>>(x, t, W_time, b_time, W_atom, b_atom,
                                    W_at, b_at, W_shared, b_shared, W_b0, b_b0,
                                    W_b1, b_b1, W_atoms, b_atoms, ws);
    k_pos<<<G_GRAPHS, 256, 0, stream>>>(pos, batch, ws, d_out);
    k_node<<<N_NODES / 16, 256, 0, stream>>>(batch, ws, hbuf, d_out);
    k_edges<<<BONDS2 + LOCAL_BLOCKS, 256, 0, stream>>>(
        eig, eil, ws, (const unsigned char*)hbuf, d_out);
}

// Round 7
// 229.631 us; speedup vs baseline: 1.1307x; 1.1307x over previous
//
#include <hip/hip_runtime.h>
#include <hip/hip_bf16.h>

typedef __hip_bfloat16 bf16;
typedef short bf16x8 __attribute__((ext_vector_type(8)));
typedef float f32x4 __attribute__((ext_vector_type(4)));
typedef float f32x2 __attribute__((ext_vector_type(2)));
typedef _Float16 f16x2 __attribute__((ext_vector_type(2)));
typedef _Float16 f16x8 __attribute__((ext_vector_type(8)));
typedef __fp16 fp16x2 __attribute__((ext_vector_type(2)));   // cvt_pkrtz result type

#define N_NODES  10000
#define G_GRAPHS 200
#define EL_EDGES 160000
#define EG_EDGES 500000
#define S_DIM    256
#define APAD     264   // k_node LDS row stride in bf16

#define BONDS2        7813    // ceil(500000 / 64): 1 wave = 16 edges, 4 waves/block
#define LOCAL_BLOCKS  625     // 160000 / 256 exact

// ---------------- workspace layout (float offsets) ----------------
#define WS_FLAG   0         // input dtype flag (0=bf16, 1=f32)
#define WS_POSC   1024      // 30000: centered positions f32
#define WS_WDH    31232     // 256 f16 (128 slots): wd CHAN-permuted
#define WS_W1F    31488     // 4096 f16 (2048 slots): W_b1 B-fragments, CHAN-mapped
#define WS_BB0R   33536     // 256: b_b0 original order (h-fold)
#define WS_BB1    34304     // 16   b_b1 (10, padded)
#define WS_WATOM  34560     // 4096 W_atom (16x256) f32
#define WS_WTIME  38656     // 256
#define WS_BTIME  38912     // 256
#define WS_BATOM  39168     // 256
#define WS_BAT    39424     // 256
#define WS_BSH    39680     // 256
#define WS_BATOMS 39936     // 32
#define WS_T      40000     // 200
#define WS_X      40448     // 160000 (N x 16) f32
#define WT_AT     200448    // 65536 bf16: W_at^T [n][k]
#define WT_SH     233216    // 65536 bf16: W_shared^T [n][k]
#define WT_B0     265984    // 65536 bf16: W_b0[:256]^T [n][k]
#define WT_ATOMS  298752    // 8192 bf16: W_atoms^T [n][k]
#define WS_H      303968    // N*256 fp8 bytes = 640,000 float slots
#define WS_END_FLOATS 944224   // ~3.78 MB

// fp8-h storage permutation: storage byte index S -> original channel.
// k_node packs dword (wave*16+l16) with channels n0+l16+{0,16,32,48}.
#define CHAN(S)    ((((S) >> 6) << 6) + (((S) & 3) << 4) + (((S) & 63) >> 2))

// ---------------- output layout (element offsets) ----------------
#define O_CPRED 0        // (N,3)
#define O_CEPS  30000    // (N,3)
#define O_APRED 60000    // (N,16)
#define O_AEPS  220000   // (N,16)
#define O_BPRED 380000   // (EG,5)
#define O_BEPS  2880000  // (EG,5)
#define O_DL    5380000  // (EL,)
#define O_RNL   5540000  // (EL,3)
#define O_AG    6020000  // (EG,)
#define O_RNG   6520000  // (EG,3)

__device__ __forceinline__ float b2f(bf16 v) { return __bfloat162float(v); }
__device__ __forceinline__ bf16  f2b(float v) { return __float2bfloat16(v); }
__device__ __forceinline__ unsigned short bbits(float v) {
    bf16 b = f2b(v);
    return *reinterpret_cast<unsigned short*>(&b);
}
__device__ __forceinline__ unsigned short h16bits(float v) {
    _Float16 h = (_Float16)v;
    return *reinterpret_cast<unsigned short*>(&h);
}
__device__ __forceinline__ float ldin(const void* p, int idx, int isf32) {
    return isf32 ? ((const float*)p)[idx] : b2f(((const bf16*)p)[idx]);
}
__device__ __forceinline__ void stout(void* out, int f32o, size_t idx, float v) {
    if (f32o) ((float*)out)[idx] = v;
    else      ((bf16*)out)[idx]  = f2b(v);
}
__device__ __forceinline__ float silu(float p) {
    return p * __builtin_amdgcn_rcpf(1.0f + __expf(-p));
}
// scalar f16 trans ops — plain VOP1 (op_sel rejected on CDNA4 trans)
__device__ __forceinline__ _Float16 h_exp2(_Float16 x) {
    _Float16 r;
    asm("v_exp_f16 %0, %1" : "=v"(r) : "v"(x));
    return r;
}
__device__ __forceinline__ _Float16 h_rcp(_Float16 x) {
    _Float16 r;
    asm("v_rcp_f16 %0, %1" : "=v"(r) : "v"(x));
    return r;
}
// packed-f16 silu: pk_mul/pk_add + 2 scalar trans per pair; saturation gives
// correct tails (p<<0: exp->inf, rcp->0, u->0; p>>0: exp->0, rcp(1)=1, u->p)
__device__ __forceinline__ f16x2 hsilu2(f16x2 p) {
    const _Float16 nl = (_Float16)(-1.44269504f);
    f16x2 q = p * (f16x2){nl, nl};
    f16x2 ex;
    ex[0] = h_exp2(q[0]);
    ex[1] = h_exp2(q[1]);
    f16x2 den = ex + (f16x2){(_Float16)1.0f, (_Float16)1.0f};
    f16x2 rc;
    rc[0] = h_rcp(den[0]);
    rc[1] = h_rcp(den[1]);
    return p * rc;
}
// fp8 pair -> f16 pair; HI must be compile-time (builtin constraint)
template<bool HI>
__device__ __forceinline__ f16x2 dec2(int enc) {
    f32x2 f = __builtin_amdgcn_cvt_pk_f32_fp8(enc, HI);
    union { fp16x2 a; f16x2 b; } u;
    u.a = __builtin_amdgcn_cvt_pkrtz(f[0], f[1]);
    return u.b;
}
// dtype sniff: t ~ U(0,1). bf16 halfwords all < 0x4000.
__device__ __forceinline__ int dtype_f32(const void* tt) {
    const unsigned short* q = (const unsigned short*)tt;
    int c = 0;
#pragma unroll
    for (int z = 0; z < 32; ++z) c += (q[z] >= 0x4000) ? 1 : 0;
    return c > 0;
}

// ---------------- canonicalize inputs; build transposed weights ----------
__global__ void k_prep(const void* __restrict__ x, const void* __restrict__ tt,
                       const void* __restrict__ W_time, const void* __restrict__ b_time,
                       const void* __restrict__ W_atom, const void* __restrict__ b_atom,
                       const void* __restrict__ W_at, const void* __restrict__ b_at,
                       const void* __restrict__ W_shared, const void* __restrict__ b_shared,
                       const void* __restrict__ W_b0, const void* __restrict__ b_b0,
                       const void* __restrict__ W_b1, const void* __restrict__ b_b1,
                       const void* __restrict__ W_atoms, const void* __restrict__ b_atoms,
                       float* __restrict__ ws) {
    const int t = blockIdx.x * blockDim.x + threadIdx.x;  // 640*256 = 163840
    const int f = dtype_f32(tt);
    if (t == 0) ws[WS_FLAG] = f ? 1.0f : 0.0f;
    if (t < 65536) {
        const int k = t >> 8, n = t & 255;
        ((unsigned short*)(ws + WT_AT))[n * 256 + k] = bbits(ldin(W_at, t, f));
        ((unsigned short*)(ws + WT_SH))[n * 256 + k] = bbits(ldin(W_shared, t, f));
        ((unsigned short*)(ws + WT_B0))[n * 256 + k] = bbits(ldin(W_b0, t, f));
    }
    if (t < 160000) ws[WS_X + t] = ldin(x, t, f);
    if (t < 8192) {
        const int k = t >> 5, n = t & 31;   // W_atoms (256,32)
        ((unsigned short*)(ws + WT_ATOMS))[n * 256 + k] = bbits(ldin(W_atoms, t, f));
    }
    if (t < 4096) {
        // W_b1 f16 B-fragments, CHAN-mapped: t = ts*512 + quad*128 + l16*8 + i
        const int i = t & 7, lc = (t >> 3) & 15, q = (t >> 7) & 3, ts = t >> 9;
        const int s = ts * 32 + q * 8 + i;          // storage channel
        float v = (lc < 10) ? ldin(W_b1, CHAN(s) * 10 + lc, f) : 0.0f;
        ((unsigned short*)(ws + WS_W1F))[t] = h16bits(v);
    }
    if (t < 4096) ws[WS_WATOM + t] = ldin(W_atom, t, f);
    if (t < 256) {
        ((unsigned short*)(ws + WS_WDH))[t] = h16bits(ldin(W_b0, 65536 + CHAN(t), f));
        ws[WS_BB0R + t] = ldin(b_b0, t, f);                // ORIGINAL order
        ws[WS_WTIME + t] = ldin(W_time, t, f);
        ws[WS_BTIME + t] = ldin(b_time, t, f);
        ws[WS_BATOM + t] = ldin(b_atom, t, f);
        ws[WS_BAT + t]   = ldin(b_at, t, f);
        ws[WS_BSH + t]   = ldin(b_shared, t, f);
    }
    if (t < 200) ws[WS_T + t] = ldin(tt, t, f);
    if (t < 32)  ws[WS_BATOMS + t] = ldin(b_atoms, t, f);
    if (t < 16)  ws[WS_BB1 + t] = (t < 10) ? ldin(b_b1, t, f) : 0.0f;
}

// ---------------- per-graph mean + center (sorted batch) -----------------
__global__ void k_pos(const void* __restrict__ pos, const int* __restrict__ batch,
                      float* __restrict__ ws, void* __restrict__ out) {
    const int g = blockIdx.x;
    const int f32o = ws[WS_FLAG] != 0.0f;
    __shared__ int s_lo, s_hi;
    __shared__ float wsum[4][3];
    __shared__ float mean[3];
    if (threadIdx.x == 0) {
        int lo = 0, hi = N_NODES;
        while (lo < hi) { int m = (lo + hi) >> 1; if (batch[m] < g) lo = m + 1; else hi = m; }
        s_lo = lo;
        int lo2 = lo; hi = N_NODES;
        while (lo2 < hi) { int m = (lo2 + hi) >> 1; if (batch[m] < g + 1) lo2 = m + 1; else hi = m; }
        s_hi = lo2;
    }
    __syncthreads();
    const int lo = s_lo, hi = s_hi, cnt = hi - lo;
    float sx = 0.f, sy = 0.f, sz = 0.f;
    for (int n = lo + threadIdx.x; n < hi; n += 256) {
        sx += ldin(pos, n * 3 + 0, f32o);
        sy += ldin(pos, n * 3 + 1, f32o);
        sz += ldin(pos, n * 3 + 2, f32o);
    }
#pragma unroll
    for (int off = 32; off > 0; off >>= 1) {
        sx += __shfl_down(sx, off);
        sy += __shfl_down(sy, off);
        sz += __shfl_down(sz, off);
    }
    if ((threadIdx.x & 63) == 0) {
        wsum[threadIdx.x >> 6][0] = sx;
        wsum[threadIdx.x >> 6][1] = sy;
        wsum[threadIdx.x >> 6][2] = sz;
    }
    __syncthreads();
    if (threadIdx.x == 0) {
        float inv = 1.0f / (float)max(cnt, 1);
        mean[0] = (wsum[0][0] + wsum[1][0] + wsum[2][0] + wsum[3][0]) * inv;
        mean[1] = (wsum[0][1] + wsum[1][1] + wsum[2][1] + wsum[3][1]) * inv;
        mean[2] = (wsum[0][2] + wsum[1][2] + wsum[2][2] + wsum[3][2]) * inv;
    }
    __syncthreads();
    for (int n = lo + threadIdx.x; n < hi; n += 256) {
#pragma unroll
        for (int k = 0; k < 3; ++k) {
            float p = ldin(pos, n * 3 + k, f32o) - mean[k];
            ws[WS_POSC + n * 3 + k] = p;
            stout(out, f32o, O_CPRED + n * 3 + k, p);
            stout(out, f32o, O_CEPS + n * 3 + k, 0.0f);
        }
    }
}

// ---------------- MFMA node pipeline: 16 rows/block, 4 waves -------------
__global__ __launch_bounds__(256) void k_node(
    const int* __restrict__ batch, const float* __restrict__ ws,
    unsigned int* __restrict__ h_out, void* __restrict__ out) {
    __shared__ unsigned short actA[16][APAD];
    __shared__ unsigned short actB[16][APAD];
    const int tid = threadIdx.x;
    const int wave = tid >> 6, lane = tid & 63;
    const int quad = lane >> 4, l16 = lane & 15;
    const int row0 = blockIdx.x * 16;

    // ---- stage 0 (VALU f32): s0 = x@W_atom + b_atom + t[batch]*W_time + b_time
    {
        const int r = tid >> 4;
        const int c0 = (tid & 15) * 16;
        const int g = row0 + r;
        float tb = ws[WS_T + batch[g]];
        float xr[16];
#pragma unroll
        for (int k = 0; k < 16; ++k) xr[k] = ws[WS_X + g * 16 + k];
        for (int cc = 0; cc < 16; cc += 4) {
            const int c = c0 + cc;
            float a0 = ws[WS_BATOM + c + 0] + tb * ws[WS_WTIME + c + 0] + ws[WS_BTIME + c + 0];
            float a1 = ws[WS_BATOM + c + 1] + tb * ws[WS_WTIME + c + 1] + ws[WS_BTIME + c + 1];
            float a2 = ws[WS_BATOM + c + 2] + tb * ws[WS_WTIME + c + 2] + ws[WS_BTIME + c + 2];
            float a3 = ws[WS_BATOM + c + 3] + tb * ws[WS_WTIME + c + 3] + ws[WS_BTIME + c + 3];
#pragma unroll
            for (int k = 0; k < 16; ++k) {
                float4 w4 = *(const float4*)(ws + WS_WATOM + k * S_DIM + c);
                a0 += xr[k] * w4.x; a1 += xr[k] * w4.y;
                a2 += xr[k] * w4.z; a3 += xr[k] * w4.w;
            }
            actA[r][c + 0] = bbits(a0); actA[r][c + 1] = bbits(a1);
            actA[r][c + 2] = bbits(a2); actA[r][c + 3] = bbits(a3);
        }
    }
    __syncthreads();

    const unsigned short* wt_at = (const unsigned short*)(ws + WT_AT);
    const unsigned short* wt_sh = (const unsigned short*)(ws + WT_SH);
    const unsigned short* wt_b0 = (const unsigned short*)(ws + WT_B0);
    const unsigned short* wt_am = (const unsigned short*)(ws + WT_ATOMS);
    const int n0 = wave * 64;

    // ---- layer 1: actB = actA @ W_at + b_at
    {
        f32x4 acc[4] = {};
        for (int kk = 0; kk < S_DIM; kk += 32) {
            const int k = kk + quad * 8;
            bf16x8 a = *(const bf16x8*)&actA[l16][k];
#pragma unroll
            for (int nt = 0; nt < 4; ++nt) {
                bf16x8 b = *(const bf16x8*)(wt_at + (size_t)(n0 + nt * 16 + l16) * S_DIM + k);
                acc[nt] = __builtin_amdgcn_mfma_f32_16x16x32_bf16(a, b, acc[nt], 0, 0, 0);
            }
        }
#pragma unroll
        for (int nt = 0; nt < 4; ++nt) {
            const int n = n0 + nt * 16 + l16;
            const float bv = ws[WS_BAT + n];
#pragma unroll
            for (int r = 0; r < 4; ++r)
                actB[quad * 4 + r][n] = bbits(acc[nt][r] + bv);
        }
    }
    __syncthreads();

    // ---- layer 2: actA = silu(actB @ W_shared + b_shared)
    {
        f32x4 acc[4] = {};
        for (int kk = 0; kk < S_DIM; kk += 32) {
            const int k = kk + quad * 8;
            bf16x8 a = *(const bf16x8*)&actB[l16][k];
#pragma unroll
            for (int nt = 0; nt < 4; ++nt) {
                bf16x8 b = *(const bf16x8*)(wt_sh + (size_t)(n0 + nt * 16 + l16) * S_DIM + k);
                acc[nt] = __builtin_amdgcn_mfma_f32_16x16x32_bf16(a, b, acc[nt], 0, 0, 0);
            }
        }
        __syncthreads();
#pragma unroll
        for (int nt = 0; nt < 4; ++nt) {
            const int n = n0 + nt * 16 + l16;
            const float bv = ws[WS_BSH + n];
#pragma unroll
            for (int r = 0; r < 4; ++r)
                actA[quad * 4 + r][n] = bbits(silu(acc[nt][r] + bv));
        }
    }
    __syncthreads();

    // ---- layer 3: h = actA @ W_b0[:256] + 0.5*b_b0, fp8 e4m3 PERMUTED pack
    {
        f32x4 acc[4] = {};
        for (int kk = 0; kk < S_DIM; kk += 32) {
            const int k = kk + quad * 8;
            bf16x8 a = *(const bf16x8*)&actA[l16][k];
#pragma unroll
            for (int nt = 0; nt < 4; ++nt) {
                bf16x8 b = *(const bf16x8*)(wt_b0 + (size_t)(n0 + nt * 16 + l16) * S_DIM + k);
                acc[nt] = __builtin_amdgcn_mfma_f32_16x16x32_bf16(a, b, acc[nt], 0, 0, 0);
            }
        }
        float bh[4];
#pragma unroll
        for (int nt = 0; nt < 4; ++nt) bh[nt] = 0.5f * ws[WS_BB0R + n0 + nt * 16 + l16];
#pragma unroll
        for (int r = 0; r < 4; ++r) {
            const int g = row0 + quad * 4 + r;
            int w = 0;
            w = __builtin_amdgcn_cvt_pk_fp8_f32(acc[0][r] + bh[0], acc[1][r] + bh[1], w, false);
            w = __builtin_amdgcn_cvt_pk_fp8_f32(acc[2][r] + bh[2], acc[3][r] + bh[3], w, true);
            h_out[(size_t)g * 64 + wave * 16 + l16] = (unsigned int)w;
        }
    }

    // ---- layer 4: atoms = actA @ W_atoms + b_atoms (256 -> 32), waves 0,1
    if (wave < 2) {
        f32x4 acc = {};
        const int n = wave * 16 + l16;
        for (int kk = 0; kk < S_DIM; kk += 32) {
            const int k = kk + quad * 8;
            bf16x8 a = *(const bf16x8*)&actA[l16][k];
            bf16x8 b = *(const bf16x8*)(wt_am + (size_t)n * S_DIM + k);
            acc = __builtin_amdgcn_mfma_f32_16x16x32_bf16(a, b, acc, 0, 0, 0);
        }
        const float bv = ws[WS_BATOMS + n];
        const int f32o = ws[WS_FLAG] != 0.0f;
#pragma unroll
        for (int r = 0; r < 4; ++r) {
            const int g = row0 + quad * 4 + r;
            float v = acc[r] + bv;
            if (n < 16) stout(out, f32o, O_AEPS + (size_t)g * 16 + n, v);
            else        stout(out, f32o, O_APRED + (size_t)g * 16 + (n - 16), v);
        }
    }
}

// ---------------- fused edges kernel: barrier-free LDS-staged bonds ------
// Blocks [0, BONDS2): global edges. One wave = 16 edges, full K=256 via 8
// f16 MFMAs. Each wave stages its 32 fp8 h-rows (16 i + 16 j) into a
// PRIVATE 8KB LDS region with coalesced 16B/lane gathers (no barriers, no
// cross-wave reduce). 16B-block XOR swizzle (blk ^= (row&15)>>1) makes the
// ds_read_b64 pattern bank-ideal. Compute: fp8->f16 decode, packed-f16
// p = h_i+h_j+d*wd, packed-f16 silu, f16 MFMA.
// Blocks [BONDS2, BONDS2+625): local edge attrs, one thread/edge.
union U8 { f16x8 v; f16x2 p[4]; };

__global__ __launch_bounds__(256, 4) void k_edges(const int* __restrict__ eig,
                                                  const int* __restrict__ eil,
                                                  const float* __restrict__ ws,
                                                  const unsigned char* __restrict__ h,
                                                  void* __restrict__ out) {
    __shared__ unsigned char sm[4][32][256];   // 32 KB: per-wave 32 rows x 256B
    const int f32o = ws[WS_FLAG] != 0.0f;

    if (blockIdx.x >= BONDS2) {
        // ---- local edges: 625 blocks x 256 threads == 160000 exact ----
        const int e = (blockIdx.x - BONDS2) * 256 + threadIdx.x;
        const float* posc = ws + WS_POSC;
        const int s = eil[e];
        const int t = eil[EL_EDGES + e];
        float rx = posc[t * 3 + 0] - posc[s * 3 + 0];
        float ry = posc[t * 3 + 1] - posc[s * 3 + 1];
        float rz = posc[t * 3 + 2] - posc[s * 3 + 2];
        float dsq = rx * rx + ry * ry + rz * rz;
        float d = sqrtf(fmaxf(dsq, 1e-6f));
        float inv = 1.0f / d;
        stout(out, f32o, O_DL + e, d);
        stout(out, f32o, O_RNL + (size_t)e * 3 + 0, rx * inv);
        stout(out, f32o, O_RNL + (size_t)e * 3 + 1, ry * inv);
        stout(out, f32o, O_RNL + (size_t)e * 3 + 2, rz * inv);
        return;
    }

    const int wave = threadIdx.x >> 6, lane = threadIdx.x & 63;
    const int quad = lane >> 4, l16 = lane & 15;
    const int e0 = blockIdx.x * 64 + wave * 16;
    if (e0 >= EG_EDGES) return;          // tail waves: safe, no barriers

    unsigned char* smw = &sm[wave][0][0];

    // ---- stage 32 rows: 16B/lane coalesced, XOR-swizzled 16B blocks ----
#pragma unroll
    for (int p = 0; p < 8; ++p) {
        const int r16 = (p & 3) * 4 + quad;            // 0..15
        const int es = e0 + r16;
        const int node = (p < 4) ? eig[EG_EDGES + es]  // rows 0-15: tgt i
                                 : eig[es];            // rows 16-31: src j
        const int row = (p < 4) ? r16 : 16 + r16;
        uint4 v = *(const uint4*)(h + (size_t)node * 256 + l16 * 16);
        *(uint4*)(smw + row * 256 + ((l16 ^ (r16 >> 1)) << 4)) = v;
    }

    // ---- geometry (per-lane; quads redundant, broadcast loads) ----
    const int e = e0 + l16;
    const int j = eig[e];                // src
    const int i = eig[EG_EDGES + e];     // tgt
    const float* posc = ws + WS_POSC;
    float pix = posc[i * 3 + 0], piy = posc[i * 3 + 1], piz = posc[i * 3 + 2];
    float pjx = posc[j * 3 + 0], pjy = posc[j * 3 + 1], pjz = posc[j * 3 + 2];
    float rx = pix - pjx, ry = piy - pjy, rz = piz - pjz;
    float dsq = rx * rx + ry * ry + rz * rz;
    float dgeo = sqrtf(dsq);             // bonds d: no clip
    if (quad == 0) {
        float ag = pix * pjx + piy * pjy + piz * pjz;
        float inv = 1.0f / sqrtf(fmaxf(dsq, 1e-6f));
        stout(out, f32o, O_AG + e, ag);
        stout(out, f32o, O_RNG + (size_t)e * 3 + 0, rx * inv);
        stout(out, f32o, O_RNG + (size_t)e * 3 + 1, ry * inv);
        stout(out, f32o, O_RNG + (size_t)e * 3 + 2, rz * inv);
    }

    const _Float16 hd = (_Float16)dgeo;
    const f16x2 d2h = {hd, hd};
    const unsigned short* wdh = (const unsigned short*)(ws + WS_WDH);
    const _Float16* w1f = (const _Float16*)(ws + WS_W1F) + (quad * 16 + l16) * 8;
    const int r2 = l16 >> 1;
    const unsigned char* rowA = smw + l16 * 256;          // h_i of edge l16
    const unsigned char* rowB = smw + (16 + l16) * 256;   // h_j of edge l16

    f32x4 acc = {};
#pragma unroll 2
    for (int t = 0; t < 8; ++t) {
        // logical k = t*32 + quad*8; 16B blk = 2t+(quad>>1), swizzled by r2
        const int off = (((2 * t + (quad >> 1)) ^ r2) << 4) + ((quad & 1) << 3);
        uint2 ua = *(const uint2*)(rowA + off);
        uint2 ub = *(const uint2*)(rowB + off);
        U8 W;  W.v = *(const f16x8*)(wdh + t * 32 + quad * 8);
        f16x8 WF = *(const f16x8*)(w1f + t * 512);
        f16x2 s0 = dec2<false>((int)ua.x) + dec2<false>((int)ub.x);
        f16x2 s1 = dec2<true>((int)ua.x)  + dec2<true>((int)ub.x);
        f16x2 s2 = dec2<false>((int)ua.y) + dec2<false>((int)ub.y);
        f16x2 s3 = dec2<true>((int)ua.y)  + dec2<true>((int)ub.y);
        U8 U;
        U.p[0] = hsilu2(s0 + d2h * W.p[0]);
        U.p[1] = hsilu2(s1 + d2h * W.p[1]);
        U.p[2] = hsilu2(s2 + d2h * W.p[2]);
        U.p[3] = hsilu2(s3 + d2h * W.p[3]);
        acc = __builtin_amdgcn_mfma_f32_16x16x32_f16(U.v, WF, acc, 0, 0, 0);
    }

    // ---- epilogue: C[row=quad*4+r][col=l16] -> bonds outputs ----
    if (l16 < 10) {
        const float bv = ws[WS_BB1 + l16];
#pragma unroll
        for (int r = 0; r < 4; ++r) {
            const int er = e0 + quad * 4 + r;
            float v = acc[r] + bv;
            if (l16 < 5) stout(out, f32o, O_BPRED + (size_t)er * 5 + l16, v);
            else         stout(out, f32o, O_BEPS + (size_t)er * 5 + (l16 - 5), v);
        }
    }
}

extern "C" void kernel_launch(void* const* d_in, const int* in_sizes, int n_in,
                              void* d_out, int out_size, void* d_ws, size_t ws_size,
                              hipStream_t stream) {
    const void* x        = d_in[0];
    const void* t        = d_in[1];
    const void* pos      = d_in[2];
    const int*  eil      = (const int*)d_in[3];
    const int*  eig      = (const int*)d_in[4];
    const int*  batch    = (const int*)d_in[6];
    const void* W_time   = d_in[7];
    const void* b_time   = d_in[8];
    const void* W_atom   = d_in[9];
    const void* b_atom   = d_in[10];
    const void* W_at     = d_in[11];
    const void* b_at     = d_in[12];
    const void* W_shared = d_in[13];
    const void* b_shared = d_in[14];
    const void* W_b0     = d_in[15];
    const void* b_b0     = d_in[16];
    const void* W_b1     = d_in[17];
    const void* b_b1     = d_in[18];
    const void* W_atoms  = d_in[20];
    const void* b_atoms  = d_in[21];
    (void)in_sizes; (void)n_in; (void)out_size;

    const size_t NEED = (size_t)WS_END_FLOATS * sizeof(float);
    if (ws_size < NEED) return;

    float* ws = (float*)d_ws;
    unsigned int* hbuf = (unsigned int*)(ws + WS_H);

    k_prep<<<640, 256, 0, stream>>>(x, t, W_time, b_time, W_atom, b_atom,
                                    W_at, b_at, W_shared, b_shared, W_b0, b_b0,
                                    W_b1, b_b1, W_atoms, b_atoms, ws);
    k_pos<<<G_GRAPHS, 256, 0, stream>>>(pos, batch, ws, d_out);
    k_node<<<N_NODES / 16, 256, 0, stream>>>(batch, ws, hbuf, d_out);
    k_edges<<<BONDS2 + LOCAL_BLOCKS, 256, 0, stream>>>(
        eig, eil, ws, (const unsigned char*)hbuf, d_out);
}

// Round 8
// 225.676 us; speedup vs baseline: 1.1505x; 1.0175x over previous
//
#include <hip/hip_runtime.h>
#include <hip/hip_bf16.h>

typedef __hip_bfloat16 bf16;
typedef short bf16x8 __attribute__((ext_vector_type(8)));
typedef float f32x4 __attribute__((ext_vector_type(4)));
typedef float f32x2 __attribute__((ext_vector_type(2)));
typedef _Float16 f16x2 __attribute__((ext_vector_type(2)));
typedef _Float16 f16x8 __attribute__((ext_vector_type(8)));
typedef __fp16 fp16x2 __attribute__((ext_vector_type(2)));   // cvt_pkrtz result type

#define N_NODES  10000
#define G_GRAPHS 200
#define EL_EDGES 160000
#define EG_EDGES 500000
#define S_DIM    256
#define APAD     264   // k_node LDS row stride in bf16

#define BONDS3        15625   // 500000 / 32: block = 2 pairs x 16 edges
#define LOCAL_BLOCKS  625     // 160000 / 256 exact

// ---------------- workspace layout (float offsets) ----------------
#define WS_FLAG   0         // input dtype flag (0=bf16, 1=f32)
#define WS_POSC   1024      // 30000: centered positions f32
#define WS_WDH    31232     // 256 f16 (128 slots): wd CHAN-permuted
#define WS_W1F    31488     // 4096 f16 (2048 slots): W_b1 B-fragments, CHAN-mapped
#define WS_BB0R   33536     // 256: b_b0 original order (h-fold)
#define WS_BB1    34304     // 16   b_b1 (10, padded)
#define WS_WATOM  34560     // 4096 W_atom (16x256) f32
#define WS_WTIME  38656     // 256
#define WS_BTIME  38912     // 256
#define WS_BATOM  39168     // 256
#define WS_BAT    39424     // 256
#define WS_BSH    39680     // 256
#define WS_BATOMS 39936     // 32
#define WS_T      40000     // 200
#define WS_X      40448     // 160000 (N x 16) f32
#define WT_AT     200448    // 65536 bf16: W_at^T [n][k]
#define WT_SH     233216    // 65536 bf16: W_shared^T [n][k]
#define WT_B0     265984    // 65536 bf16: W_b0[:256]^T [n][k]
#define WT_ATOMS  298752    // 8192 bf16: W_atoms^T [n][k]
#define WS_H      303968    // N*256 fp8 bytes = 640,000 float slots
#define WS_END_FLOATS 944224   // ~3.78 MB

// fp8-h storage permutation: storage byte index S -> original channel.
// k_node packs dword (wave*16+l16) with channels n0+l16+{0,16,32,48}.
#define CHAN(S)    ((((S) >> 6) << 6) + (((S) & 3) << 4) + (((S) & 63) >> 2))

// ---------------- output layout (element offsets) ----------------
#define O_CPRED 0        // (N,3)
#define O_CEPS  30000    // (N,3)
#define O_APRED 60000    // (N,16)
#define O_AEPS  220000   // (N,16)
#define O_BPRED 380000   // (EG,5)
#define O_BEPS  2880000  // (EG,5)
#define O_DL    5380000  // (EL,)
#define O_RNL   5540000  // (EL,3)
#define O_AG    6020000  // (EG,)
#define O_RNG   6520000  // (EG,3)

__device__ __forceinline__ float b2f(bf16 v) { return __bfloat162float(v); }
__device__ __forceinline__ bf16  f2b(float v) { return __float2bfloat16(v); }
__device__ __forceinline__ unsigned short bbits(float v) {
    bf16 b = f2b(v);
    return *reinterpret_cast<unsigned short*>(&b);
}
__device__ __forceinline__ unsigned short h16bits(float v) {
    _Float16 h = (_Float16)v;
    return *reinterpret_cast<unsigned short*>(&h);
}
__device__ __forceinline__ float ldin(const void* p, int idx, int isf32) {
    return isf32 ? ((const float*)p)[idx] : b2f(((const bf16*)p)[idx]);
}
__device__ __forceinline__ void stout(void* out, int f32o, size_t idx, float v) {
    if (f32o) ((float*)out)[idx] = v;
    else      ((bf16*)out)[idx]  = f2b(v);
}
__device__ __forceinline__ float silu(float p) {
    return p * __builtin_amdgcn_rcpf(1.0f + __expf(-p));
}
// scalar f16 trans ops — plain VOP1 (op_sel rejected on CDNA4 trans)
__device__ __forceinline__ _Float16 h_exp2(_Float16 x) {
    _Float16 r;
    asm("v_exp_f16 %0, %1" : "=v"(r) : "v"(x));
    return r;
}
__device__ __forceinline__ _Float16 h_rcp(_Float16 x) {
    _Float16 r;
    asm("v_rcp_f16 %0, %1" : "=v"(r) : "v"(x));
    return r;
}
// packed-f16 silu: pk_mul/pk_add + 2 scalar trans per pair; saturation gives
// correct tails (p<<0: exp->inf, rcp->0, u->0; p>>0: exp->0, rcp(1)=1, u->p)
__device__ __forceinline__ f16x2 hsilu2(f16x2 p) {
    const _Float16 nl = (_Float16)(-1.44269504f);
    f16x2 q = p * (f16x2){nl, nl};
    f16x2 ex;
    ex[0] = h_exp2(q[0]);
    ex[1] = h_exp2(q[1]);
    f16x2 den = ex + (f16x2){(_Float16)1.0f, (_Float16)1.0f};
    f16x2 rc;
    rc[0] = h_rcp(den[0]);
    rc[1] = h_rcp(den[1]);
    return p * rc;
}
// fp8 pair -> f16 pair; HI must be compile-time (builtin constraint).
// Prefer gfx950 direct fp8->f16 (1 op, scale=1.0); fallback to proven 2-op path.
#if defined(__has_builtin)
#if __has_builtin(__builtin_amdgcn_cvt_scalef32_pk_f16_fp8)
#define HAVE_SCALEF16 1
#endif
#endif
template<bool HI>
__device__ __forceinline__ f16x2 dec2(int enc) {
#ifdef HAVE_SCALEF16
    auto r = __builtin_amdgcn_cvt_scalef32_pk_f16_fp8((unsigned int)enc, 1.0f, HI);
    return __builtin_bit_cast(f16x2, r);
#else
    f32x2 f = __builtin_amdgcn_cvt_pk_f32_fp8(enc, HI);
    union { fp16x2 a; f16x2 b; } u;
    u.a = __builtin_amdgcn_cvt_pkrtz(f[0], f[1]);
    return u.b;
#endif
}
// dtype sniff: t ~ U(0,1). bf16 halfwords all < 0x4000.
__device__ __forceinline__ int dtype_f32(const void* tt) {
    const unsigned short* q = (const unsigned short*)tt;
    int c = 0;
#pragma unroll
    for (int z = 0; z < 32; ++z) c += (q[z] >= 0x4000) ? 1 : 0;
    return c > 0;
}

// ---------------- canonicalize inputs; build transposed weights ----------
__global__ void k_prep(const void* __restrict__ x, const void* __restrict__ tt,
                       const void* __restrict__ W_time, const void* __restrict__ b_time,
                       const void* __restrict__ W_atom, const void* __restrict__ b_atom,
                       const void* __restrict__ W_at, const void* __restrict__ b_at,
                       const void* __restrict__ W_shared, const void* __restrict__ b_shared,
                       const void* __restrict__ W_b0, const void* __restrict__ b_b0,
                       const void* __restrict__ W_b1, const void* __restrict__ b_b1,
                       const void* __restrict__ W_atoms, const void* __restrict__ b_atoms,
                       float* __restrict__ ws) {
    const int t = blockIdx.x * blockDim.x + threadIdx.x;  // 640*256 = 163840
    const int f = dtype_f32(tt);
    if (t == 0) ws[WS_FLAG] = f ? 1.0f : 0.0f;
    if (t < 65536) {
        const int k = t >> 8, n = t & 255;
        ((unsigned short*)(ws + WT_AT))[n * 256 + k] = bbits(ldin(W_at, t, f));
        ((unsigned short*)(ws + WT_SH))[n * 256 + k] = bbits(ldin(W_shared, t, f));
        ((unsigned short*)(ws + WT_B0))[n * 256 + k] = bbits(ldin(W_b0, t, f));
    }
    if (t < 160000) ws[WS_X + t] = ldin(x, t, f);
    if (t < 8192) {
        const int k = t >> 5, n = t & 31;   // W_atoms (256,32)
        ((unsigned short*)(ws + WT_ATOMS))[n * 256 + k] = bbits(ldin(W_atoms, t, f));
    }
    if (t < 4096) {
        // W_b1 f16 B-fragments, CHAN-mapped: t = ts*512 + quad*128 + l16*8 + i
        const int i = t & 7, lc = (t >> 3) & 15, q = (t >> 7) & 3, ts = t >> 9;
        const int s = ts * 32 + q * 8 + i;          // storage channel
        float v = (lc < 10) ? ldin(W_b1, CHAN(s) * 10 + lc, f) : 0.0f;
        ((unsigned short*)(ws + WS_W1F))[t] = h16bits(v);
    }
    if (t < 4096) ws[WS_WATOM + t] = ldin(W_atom, t, f);
    if (t < 256) {
        ((unsigned short*)(ws + WS_WDH))[t] = h16bits(ldin(W_b0, 65536 + CHAN(t), f));
        ws[WS_BB0R + t] = ldin(b_b0, t, f);                // ORIGINAL order
        ws[WS_WTIME + t] = ldin(W_time, t, f);
        ws[WS_BTIME + t] = ldin(b_time, t, f);
        ws[WS_BATOM + t] = ldin(b_atom, t, f);
        ws[WS_BAT + t]   = ldin(b_at, t, f);
        ws[WS_BSH + t]   = ldin(b_shared, t, f);
    }
    if (t < 200) ws[WS_T + t] = ldin(tt, t, f);
    if (t < 32)  ws[WS_BATOMS + t] = ldin(b_atoms, t, f);
    if (t < 16)  ws[WS_BB1 + t] = (t < 10) ? ldin(b_b1, t, f) : 0.0f;
}

// ---------------- per-graph mean + center (sorted batch) -----------------
__global__ void k_pos(const void* __restrict__ pos, const int* __restrict__ batch,
                      float* __restrict__ ws, void* __restrict__ out) {
    const int g = blockIdx.x;
    const int f32o = ws[WS_FLAG] != 0.0f;
    __shared__ int s_lo, s_hi;
    __shared__ float wsum[4][3];
    __shared__ float mean[3];
    if (threadIdx.x == 0) {
        int lo = 0, hi = N_NODES;
        while (lo < hi) { int m = (lo + hi) >> 1; if (batch[m] < g) lo = m + 1; else hi = m; }
        s_lo = lo;
        int lo2 = lo; hi = N_NODES;
        while (lo2 < hi) { int m = (lo2 + hi) >> 1; if (batch[m] < g + 1) lo2 = m + 1; else hi = m; }
        s_hi = lo2;
    }
    __syncthreads();
    const int lo = s_lo, hi = s_hi, cnt = hi - lo;
    float sx = 0.f, sy = 0.f, sz = 0.f;
    for (int n = lo + threadIdx.x; n < hi; n += 256) {
        sx += ldin(pos, n * 3 + 0, f32o);
        sy += ldin(pos, n * 3 + 1, f32o);
        sz += ldin(pos, n * 3 + 2, f32o);
    }
#pragma unroll
    for (int off = 32; off > 0; off >>= 1) {
        sx += __shfl_down(sx, off);
        sy += __shfl_down(sy, off);
        sz += __shfl_down(sz, off);
    }
    if ((threadIdx.x & 63) == 0) {
        wsum[threadIdx.x >> 6][0] = sx;
        wsum[threadIdx.x >> 6][1] = sy;
        wsum[threadIdx.x >> 6][2] = sz;
    }
    __syncthreads();
    if (threadIdx.x == 0) {
        float inv = 1.0f / (float)max(cnt, 1);
        mean[0] = (wsum[0][0] + wsum[1][0] + wsum[2][0] + wsum[3][0]) * inv;
        mean[1] = (wsum[0][1] + wsum[1][1] + wsum[2][1] + wsum[3][1]) * inv;
        mean[2] = (wsum[0][2] + wsum[1][2] + wsum[2][2] + wsum[3][2]) * inv;
    }
    __syncthreads();
    for (int n = lo + threadIdx.x; n < hi; n += 256) {
#pragma unroll
        for (int k = 0; k < 3; ++k) {
            float p = ldin(pos, n * 3 + k, f32o) - mean[k];
            ws[WS_POSC + n * 3 + k] = p;
            stout(out, f32o, O_CPRED + n * 3 + k, p);
            stout(out, f32o, O_CEPS + n * 3 + k, 0.0f);
        }
    }
}

// ---------------- MFMA node pipeline: 16 rows/block, 4 waves -------------
__global__ __launch_bounds__(256) void k_node(
    const int* __restrict__ batch, const float* __restrict__ ws,
    unsigned int* __restrict__ h_out, void* __restrict__ out) {
    __shared__ unsigned short actA[16][APAD];
    __shared__ unsigned short actB[16][APAD];
    const int tid = threadIdx.x;
    const int wave = tid >> 6, lane = tid & 63;
    const int quad = lane >> 4, l16 = lane & 15;
    const int row0 = blockIdx.x * 16;

    // ---- stage 0 (VALU f32): s0 = x@W_atom + b_atom + t[batch]*W_time + b_time
    {
        const int r = tid >> 4;
        const int c0 = (tid & 15) * 16;
        const int g = row0 + r;
        float tb = ws[WS_T + batch[g]];
        float xr[16];
#pragma unroll
        for (int k = 0; k < 16; ++k) xr[k] = ws[WS_X + g * 16 + k];
        for (int cc = 0; cc < 16; cc += 4) {
            const int c = c0 + cc;
            float a0 = ws[WS_BATOM + c + 0] + tb * ws[WS_WTIME + c + 0] + ws[WS_BTIME + c + 0];
            float a1 = ws[WS_BATOM + c + 1] + tb * ws[WS_WTIME + c + 1] + ws[WS_BTIME + c + 1];
            float a2 = ws[WS_BATOM + c + 2] + tb * ws[WS_WTIME + c + 2] + ws[WS_BTIME + c + 2];
            float a3 = ws[WS_BATOM + c + 3] + tb * ws[WS_WTIME + c + 3] + ws[WS_BTIME + c + 3];
#pragma unroll
            for (int k = 0; k < 16; ++k) {
                float4 w4 = *(const float4*)(ws + WS_WATOM + k * S_DIM + c);
                a0 += xr[k] * w4.x; a1 += xr[k] * w4.y;
                a2 += xr[k] * w4.z; a3 += xr[k] * w4.w;
            }
            actA[r][c + 0] = bbits(a0); actA[r][c + 1] = bbits(a1);
            actA[r][c + 2] = bbits(a2); actA[r][c + 3] = bbits(a3);
        }
    }
    __syncthreads();

    const unsigned short* wt_at = (const unsigned short*)(ws + WT_AT);
    const unsigned short* wt_sh = (const unsigned short*)(ws + WT_SH);
    const unsigned short* wt_b0 = (const unsigned short*)(ws + WT_B0);
    const unsigned short* wt_am = (const unsigned short*)(ws + WT_ATOMS);
    const int n0 = wave * 64;

    // ---- layer 1: actB = actA @ W_at + b_at
    {
        f32x4 acc[4] = {};
        for (int kk = 0; kk < S_DIM; kk += 32) {
            const int k = kk + quad * 8;
            bf16x8 a = *(const bf16x8*)&actA[l16][k];
#pragma unroll
            for (int nt = 0; nt < 4; ++nt) {
                bf16x8 b = *(const bf16x8*)(wt_at + (size_t)(n0 + nt * 16 + l16) * S_DIM + k);
                acc[nt] = __builtin_amdgcn_mfma_f32_16x16x32_bf16(a, b, acc[nt], 0, 0, 0);
            }
        }
#pragma unroll
        for (int nt = 0; nt < 4; ++nt) {
            const int n = n0 + nt * 16 + l16;
            const float bv = ws[WS_BAT + n];
#pragma unroll
            for (int r = 0; r < 4; ++r)
                actB[quad * 4 + r][n] = bbits(acc[nt][r] + bv);
        }
    }
    __syncthreads();

    // ---- layer 2: actA = silu(actB @ W_shared + b_shared)
    {
        f32x4 acc[4] = {};
        for (int kk = 0; kk < S_DIM; kk += 32) {
            const int k = kk + quad * 8;
            bf16x8 a = *(const bf16x8*)&actB[l16][k];
#pragma unroll
            for (int nt = 0; nt < 4; ++nt) {
                bf16x8 b = *(const bf16x8*)(wt_sh + (size_t)(n0 + nt * 16 + l16) * S_DIM + k);
                acc[nt] = __builtin_amdgcn_mfma_f32_16x16x32_bf16(a, b, acc[nt], 0, 0, 0);
            }
        }
        __syncthreads();
#pragma unroll
        for (int nt = 0; nt < 4; ++nt) {
            const int n = n0 + nt * 16 + l16;
            const float bv = ws[WS_BSH + n];
#pragma unroll
            for (int r = 0; r < 4; ++r)
                actA[quad * 4 + r][n] = bbits(silu(acc[nt][r] + bv));
        }
    }
    __syncthreads();

    // ---- layer 3: h = actA @ W_b0[:256] + 0.5*b_b0, fp8 e4m3 PERMUTED pack
    {
        f32x4 acc[4] = {};
        for (int kk = 0; kk < S_DIM; kk += 32) {
            const int k = kk + quad * 8;
            bf16x8 a = *(const bf16x8*)&actA[l16][k];
#pragma unroll
            for (int nt = 0; nt < 4; ++nt) {
                bf16x8 b = *(const bf16x8*)(wt_b0 + (size_t)(n0 + nt * 16 + l16) * S_DIM + k);
                acc[nt] = __builtin_amdgcn_mfma_f32_16x16x32_bf16(a, b, acc[nt], 0, 0, 0);
            }
        }
        float bh[4];
#pragma unroll
        for (int nt = 0; nt < 4; ++nt) bh[nt] = 0.5f * ws[WS_BB0R + n0 + nt * 16 + l16];
#pragma unroll
        for (int r = 0; r < 4; ++r) {
            const int g = row0 + quad * 4 + r;
            int w = 0;
            w = __builtin_amdgcn_cvt_pk_fp8_f32(acc[0][r] + bh[0], acc[1][r] + bh[1], w, false);
            w = __builtin_amdgcn_cvt_pk_fp8_f32(acc[2][r] + bh[2], acc[3][r] + bh[3], w, true);
            h_out[(size_t)g * 64 + wave * 16 + l16] = (unsigned int)w;
        }
    }

    // ---- layer 4: atoms = actA @ W_atoms + b_atoms (256 -> 32), waves 0,1
    if (wave < 2) {
        f32x4 acc = {};
        const int n = wave * 16 + l16;
        for (int kk = 0; kk < S_DIM; kk += 32) {
            const int k = kk + quad * 8;
            bf16x8 a = *(const bf16x8*)&actA[l16][k];
            bf16x8 b = *(const bf16x8*)(wt_am + (size_t)n * S_DIM + k);
            acc = __builtin_amdgcn_mfma_f32_16x16x32_bf16(a, b, acc, 0, 0, 0);
        }
        const float bv = ws[WS_BATOMS + n];
        const int f32o = ws[WS_FLAG] != 0.0f;
#pragma unroll
        for (int r = 0; r < 4; ++r) {
            const int g = row0 + quad * 4 + r;
            float v = acc[r] + bv;
            if (n < 16) stout(out, f32o, O_AEPS + (size_t)g * 16 + n, v);
            else        stout(out, f32o, O_APRED + (size_t)g * 16 + (n - 16), v);
        }
    }
}

// ---------------- fused edges kernel: K-split pair, 16KB LDS -------------
// Blocks [0, BONDS3): 32 edges/block = 2 pairs x 16 edges. Each wave of a
// pair computes K-half sub*128..+128 (4 f16 MFMAs); stages 32 half-rows
// (128B) of fp8 h into a PRIVATE 4KB LDS region (barrier-free staging),
// XOR-swizzled (blk ^= row&7) for bank-balanced b64 reads. One barrier for
// the cross-wave K-reduction. 16KB LDS/block -> occupancy cap 100%.
// Blocks [BONDS3, BONDS3+625): local edge attrs, one thread/edge.
union U8 { f16x8 v; f16x2 p[4]; };

__global__ __launch_bounds__(256, 8) void k_edges(const int* __restrict__ eig,
                                                  const int* __restrict__ eil,
                                                  const float* __restrict__ ws,
                                                  const unsigned char* __restrict__ h,
                                                  void* __restrict__ out) {
    __shared__ __align__(16) unsigned char sm[4][32][128];   // 16 KB
    const int f32o = ws[WS_FLAG] != 0.0f;

    if (blockIdx.x >= BONDS3) {
        // ---- local edges: 625 blocks x 256 threads == 160000 exact ----
        const int e = (blockIdx.x - BONDS3) * 256 + threadIdx.x;
        const float* posc = ws + WS_POSC;
        const int s = eil[e];
        const int t = eil[EL_EDGES + e];
        float rx = posc[t * 3 + 0] - posc[s * 3 + 0];
        float ry = posc[t * 3 + 1] - posc[s * 3 + 1];
        float rz = posc[t * 3 + 2] - posc[s * 3 + 2];
        float dsq = rx * rx + ry * ry + rz * rz;
        float d = sqrtf(fmaxf(dsq, 1e-6f));
        float inv = 1.0f / d;
        stout(out, f32o, O_DL + e, d);
        stout(out, f32o, O_RNL + (size_t)e * 3 + 0, rx * inv);
        stout(out, f32o, O_RNL + (size_t)e * 3 + 1, ry * inv);
        stout(out, f32o, O_RNL + (size_t)e * 3 + 2, rz * inv);
        return;
    }

    const int wave = threadIdx.x >> 6, lane = threadIdx.x & 63;
    const int quad = lane >> 4, l16 = lane & 15;
    const int P = wave >> 1, sub = wave & 1;
    const int e0 = blockIdx.x * 32 + P * 16;   // 15625*32 == 500000 exact
    unsigned char* smw = &sm[wave][0][0];

    // ---- stage 32 half-rows (128B): 4 passes x 8 rows, 16B/lane ----
    const int l8 = lane & 7, rg = lane >> 3;
#pragma unroll
    for (int p = 0; p < 4; ++p) {
        const int row = p * 8 + rg;                    // 0..31
        const int r16 = row & 15;
        const int es = e0 + r16;
        const int node = (row < 16) ? eig[EG_EDGES + es]   // rows 0-15: tgt i
                                    : eig[es];             // rows 16-31: src j
        uint4 v = *(const uint4*)(h + (size_t)node * 256 + sub * 128 + l8 * 16);
        *(uint4*)(smw + row * 128 + ((l8 ^ (row & 7)) << 4)) = v;
    }

    // ---- geometry: both subs compute d; sub0/quad0 writes outputs ----
    const int e = e0 + l16;
    const int j = eig[e];                // src
    const int i = eig[EG_EDGES + e];     // tgt
    const float* posc = ws + WS_POSC;
    float pix = posc[i * 3 + 0], piy = posc[i * 3 + 1], piz = posc[i * 3 + 2];
    float pjx = posc[j * 3 + 0], pjy = posc[j * 3 + 1], pjz = posc[j * 3 + 2];
    float rx = pix - pjx, ry = piy - pjy, rz = piz - pjz;
    float dsq = rx * rx + ry * ry + rz * rz;
    float dgeo = sqrtf(dsq);             // bonds d: no clip
    if (sub == 0 && quad == 0) {
        float ag = pix * pjx + piy * pjy + piz * pjz;
        float inv = 1.0f / sqrtf(fmaxf(dsq, 1e-6f));
        stout(out, f32o, O_AG + e, ag);
        stout(out, f32o, O_RNG + (size_t)e * 3 + 0, rx * inv);
        stout(out, f32o, O_RNG + (size_t)e * 3 + 1, ry * inv);
        stout(out, f32o, O_RNG + (size_t)e * 3 + 2, rz * inv);
    }

    const _Float16 hd = (_Float16)dgeo;
    const f16x2 d2h = {hd, hd};
    const unsigned short* wdh = (const unsigned short*)(ws + WS_WDH) + sub * 128;
    const _Float16* w1f = (const _Float16*)(ws + WS_W1F)
                        + (size_t)(sub * 4) * 512 + (quad * 16 + l16) * 8;
    const int rx7 = l16 & 7;
    const unsigned char* rowA = smw + l16 * 128;          // h_i half of edge l16
    const unsigned char* rowB = smw + (16 + l16) * 128;   // h_j half of edge l16

    f32x4 acc = {};
#pragma unroll
    for (int t = 0; t < 4; ++t) {
        // local k = t*32 + quad*8; 16B blk = 2t+(quad>>1), swizzled by rx7
        const int off = (((2 * t + (quad >> 1)) ^ rx7) << 4) + ((quad & 1) << 3);
        uint2 ua = *(const uint2*)(rowA + off);
        uint2 ub = *(const uint2*)(rowB + off);
        U8 W;  W.v = *(const f16x8*)(wdh + t * 32 + quad * 8);
        f16x8 WF = *(const f16x8*)(w1f + t * 512);
        f16x2 s0 = dec2<false>((int)ua.x) + dec2<false>((int)ub.x);
        f16x2 s1 = dec2<true>((int)ua.x)  + dec2<true>((int)ub.x);
        f16x2 s2 = dec2<false>((int)ua.y) + dec2<false>((int)ub.y);
        f16x2 s3 = dec2<true>((int)ua.y)  + dec2<true>((int)ub.y);
        U8 U;
        U.p[0] = hsilu2(s0 + d2h * W.p[0]);
        U.p[1] = hsilu2(s1 + d2h * W.p[1]);
        U.p[2] = hsilu2(s2 + d2h * W.p[2]);
        U.p[3] = hsilu2(s3 + d2h * W.p[3]);
        acc = __builtin_amdgcn_mfma_f32_16x16x32_f16(U.v, WF, acc, 0, 0, 0);
    }

    // ---- cross-wave K-reduction (sub1 -> sub0 via sub1's dead region) ----
    if (sub == 1) ((f32x4*)smw)[lane] = acc;
    __syncthreads();
    if (sub == 0 && l16 < 10) {
        f32x4 o = ((f32x4*)(smw + 4096))[lane];   // partner (sub1) region
        const float bv = ws[WS_BB1 + l16];
#pragma unroll
        for (int r = 0; r < 4; ++r) {
            const int er = e0 + quad * 4 + r;
            float v = acc[r] + o[r] + bv;
            if (l16 < 5) stout(out, f32o, O_BPRED + (size_t)er * 5 + l16, v);
            else         stout(out, f32o, O_BEPS + (size_t)er * 5 + (l16 - 5), v);
        }
    }
}

extern "C" void kernel_launch(void* const* d_in, const int* in_sizes, int n_in,
                              void* d_out, int out_size, void* d_ws, size_t ws_size,
                              hipStream_t stream) {
    const void* x        = d_in[0];
    const void* t        = d_in[1];
    const void* pos      = d_in[2];
    const int*  eil      = (const int*)d_in[3];
    const int*  eig      = (const int*)d_in[4];
    const int*  batch    = (const int*)d_in[6];
    const void* W_time   = d_in[7];
    const void* b_time   = d_in[8];
    const void* W_atom   = d_in[9];
    const void* b_atom   = d_in[10];
    const void* W_at     = d_in[11];
    const void* b_at     = d_in[12];
    const void* W_shared = d_in[13];
    const void* b_shared = d_in[14];
    const void* W_b0     = d_in[15];
    const void* b_b0     = d_in[16];
    const void* W_b1     = d_in[17];
    const void* b_b1     = d_in[18];
    const void* W_atoms  = d_in[20];
    const void* b_atoms  = d_in[21];
    (void)in_sizes; (void)n_in; (void)out_size;

    const size_t NEED = (size_t)WS_END_FLOATS * sizeof(float);
    if (ws_size < NEED) return;

    float* ws = (float*)d_ws;
    unsigned int* hbuf = (unsigned int*)(ws + WS_H);

    k_prep<<<640, 256, 0, stream>>>(x, t, W_time, b_time, W_atom, b_atom,
                                    W_at, b_at, W_shared, b_shared, W_b0, b_b0,
                                    W_b1, b_b1, W_atoms, b_atoms, ws);
    k_pos<<<G_GRAPHS, 256, 0, stream>>>(pos, batch, ws, d_out);
    k_node<<<N_NODES / 16, 256, 0, stream>>>(batch, ws, hbuf, d_out);
    k_edges<<<BONDS3 + LOCAL_BLOCKS, 256, 0, stream>>>(
        eig, eil, ws, (const unsigned char*)hbuf, d_out);
}

// Round 10
// 216.763 us; speedup vs baseline: 1.1978x; 1.0411x over previous
//
#include <hip/hip_runtime.h>
#include <hip/hip_bf16.h>

typedef __hip_bfloat16 bf16;
typedef short bf16x8 __attribute__((ext_vector_type(8)));
typedef float f32x4 __attribute__((ext_vector_type(4)));
typedef float f32x2 __attribute__((ext_vector_type(2)));
typedef _Float16 f16x2 __attribute__((ext_vector_type(2)));
typedef _Float16 f16x8 __attribute__((ext_vector_type(8)));
typedef __fp16 fp16x2 __attribute__((ext_vector_type(2)));   // cvt_pkrtz result type

#define N_NODES  10000
#define G_GRAPHS 200
#define EL_EDGES 160000
#define EG_EDGES 500000
#define S_DIM    256
#define APAD     264   // k_node LDS row stride in bf16

#define PREP_BLOCKS   640     // t < 163840 covers all prep work
#define NODE_BLOCKS   625     // 10000 / 16
#define BONDS3        15625   // 500000 / 32: block = 2 pairs x 16 edges
#define LOCAL_BLOCKS  625     // 160000 / 256 exact

// ---------------- workspace layout (float offsets) ----------------
#define WS_FLAG   0         // input dtype flag (0=bf16, 1=f32)
#define WS_POSC   1024      // 30000: centered positions f32
#define WS_WDH    31232     // 256 f16 (128 slots): wd CHAN-permuted
#define WS_W1F    31488     // 4096 f16 (2048 slots): W_b1 B-fragments, CHAN-mapped
#define WS_BB0R   33536     // 256: b_b0 original order (h-fold)
#define WS_BB1    34304     // 16   b_b1 (10, padded)
#define WS_WATOM  34560     // 4096 W_atom (16x256) f32
#define WS_WTIME  38656     // 256
#define WS_BTIME  38912     // 256
#define WS_BATOM  39168     // 256
#define WS_BAT    39424     // 256
#define WS_BSH    39680     // 256
#define WS_BATOMS 39936     // 32
#define WS_T      40000     // 200
#define WS_X      40448     // 160000 (N x 16) f32
#define WT_AT     200448    // 65536 bf16: W_at^T [n][k]
#define WT_SH     233216    // 65536 bf16: W_shared^T [n][k]
#define WT_B0     265984    // 65536 bf16: W_b0[:256]^T [n][k]
#define WT_ATOMS  298752    // 8192 bf16: W_atoms^T [n][k]
#define WS_H      303968    // N*256 fp8 bytes = 640,000 float slots
#define WS_END_FLOATS 944224   // ~3.78 MB

// fp8-h storage permutation: storage byte index S -> original channel.
// k_node packs dword (wave*16+l16) with channels n0+l16+{0,16,32,48}.
#define CHAN(S)    ((((S) >> 6) << 6) + (((S) & 3) << 4) + (((S) & 63) >> 2))

// ---------------- output layout (element offsets) ----------------
#define O_CPRED 0        // (N,3)
#define O_CEPS  30000    // (N,3)
#define O_APRED 60000    // (N,16)
#define O_AEPS  220000   // (N,16)
#define O_BPRED 380000   // (EG,5)
#define O_BEPS  2880000  // (EG,5)
#define O_DL    5380000  // (EL,)
#define O_RNL   5540000  // (EL,3)
#define O_AG    6020000  // (EG,)
#define O_RNG   6520000  // (EG,3)

__device__ __forceinline__ float b2f(bf16 v) { return __bfloat162float(v); }
__device__ __forceinline__ bf16  f2b(float v) { return __float2bfloat16(v); }
__device__ __forceinline__ unsigned short bbits(float v) {
    bf16 b = f2b(v);
    return *reinterpret_cast<unsigned short*>(&b);
}
__device__ __forceinline__ unsigned short h16bits(float v) {
    _Float16 h = (_Float16)v;
    return *reinterpret_cast<unsigned short*>(&h);
}
__device__ __forceinline__ float ldin(const void* p, int idx, int isf32) {
    return isf32 ? ((const float*)p)[idx] : b2f(((const bf16*)p)[idx]);
}
__device__ __forceinline__ void stout(void* out, int f32o, size_t idx, float v) {
    if (f32o) ((float*)out)[idx] = v;
    else      ((bf16*)out)[idx]  = f2b(v);
}
__device__ __forceinline__ float silu(float p) {
    return p * __builtin_amdgcn_rcpf(1.0f + __expf(-p));
}
// scalar f16 trans ops — plain VOP1 (op_sel rejected on CDNA4 trans)
__device__ __forceinline__ _Float16 h_exp2(_Float16 x) {
    _Float16 r;
    asm("v_exp_f16 %0, %1" : "=v"(r) : "v"(x));
    return r;
}
__device__ __forceinline__ _Float16 h_rcp(_Float16 x) {
    _Float16 r;
    asm("v_rcp_f16 %0, %1" : "=v"(r) : "v"(x));
    return r;
}
// packed-f16 silu: pk_mul/pk_add + 2 scalar trans per pair; saturation gives
// correct tails (p<<0: exp->inf, rcp->0, u->0; p>>0: exp->0, rcp(1)=1, u->p)
__device__ __forceinline__ f16x2 hsilu2(f16x2 p) {
    const _Float16 nl = (_Float16)(-1.44269504f);
    f16x2 q = p * (f16x2){nl, nl};
    f16x2 ex;
    ex[0] = h_exp2(q[0]);
    ex[1] = h_exp2(q[1]);
    f16x2 den = ex + (f16x2){(_Float16)1.0f, (_Float16)1.0f};
    f16x2 rc;
    rc[0] = h_rcp(den[0]);
    rc[1] = h_rcp(den[1]);
    return p * rc;
}
// fp8 pair -> f16 pair; HI must be compile-time (builtin constraint).
// Prefer gfx950 direct fp8->f16 (1 op, scale=1.0); fallback to proven 2-op path.
#if defined(__has_builtin)
#if __has_builtin(__builtin_amdgcn_cvt_scalef32_pk_f16_fp8)
#define HAVE_SCALEF16 1
#endif
#endif
template<bool HI>
__device__ __forceinline__ f16x2 dec2(int enc) {
#ifdef HAVE_SCALEF16
    auto r = __builtin_amdgcn_cvt_scalef32_pk_f16_fp8((unsigned int)enc, 1.0f, HI);
    return __builtin_bit_cast(f16x2, r);
#else
    f32x2 f = __builtin_amdgcn_cvt_pk_f32_fp8(enc, HI);
    union { fp16x2 a; f16x2 b; } u;
    u.a = __builtin_amdgcn_cvt_pkrtz(f[0], f[1]);
    return u.b;
#endif
}
// dtype sniff: t ~ U(0,1). bf16 halfwords all < 0x4000.
__device__ __forceinline__ int dtype_f32(const void* tt) {
    const unsigned short* q = (const unsigned short*)tt;
    int c = 0;
#pragma unroll
    for (int z = 0; z < 32; ++z) c += (q[z] >= 0x4000) ? 1 : 0;
    return c > 0;
}

// -------- merged prep + per-graph centering (blocks >= PREP_BLOCKS) -------
__global__ void k_prep(const void* __restrict__ x, const void* __restrict__ tt,
                       const void* __restrict__ W_time, const void* __restrict__ b_time,
                       const void* __restrict__ W_atom, const void* __restrict__ b_atom,
                       const void* __restrict__ W_at, const void* __restrict__ b_at,
                       const void* __restrict__ W_shared, const void* __restrict__ b_shared,
                       const void* __restrict__ W_b0, const void* __restrict__ b_b0,
                       const void* __restrict__ W_b1, const void* __restrict__ b_b1,
                       const void* __restrict__ W_atoms, const void* __restrict__ b_atoms,
                       const void* __restrict__ pos, const int* __restrict__ batch,
                       float* __restrict__ ws, void* __restrict__ out) {
    if (blockIdx.x >= PREP_BLOCKS) {
        // ---- k_pos part: one block per graph; flag computed locally ----
        const int g = blockIdx.x - PREP_BLOCKS;
        const int f32o = dtype_f32(tt);
        __shared__ int s_lo, s_hi;
        __shared__ float wsum[4][3];
        __shared__ float mean[3];
        if (threadIdx.x == 0) {
            int lo = 0, hi = N_NODES;
            while (lo < hi) { int m = (lo + hi) >> 1; if (batch[m] < g) lo = m + 1; else hi = m; }
            s_lo = lo;
            int lo2 = lo; hi = N_NODES;
            while (lo2 < hi) { int m = (lo2 + hi) >> 1; if (batch[m] < g + 1) lo2 = m + 1; else hi = m; }
            s_hi = lo2;
        }
        __syncthreads();
        const int lo = s_lo, hi = s_hi, cnt = hi - lo;
        float sx = 0.f, sy = 0.f, sz = 0.f;
        for (int n = lo + threadIdx.x; n < hi; n += 256) {
            sx += ldin(pos, n * 3 + 0, f32o);
            sy += ldin(pos, n * 3 + 1, f32o);
            sz += ldin(pos, n * 3 + 2, f32o);
        }
#pragma unroll
        for (int off = 32; off > 0; off >>= 1) {
            sx += __shfl_down(sx, off);
            sy += __shfl_down(sy, off);
            sz += __shfl_down(sz, off);
        }
        if ((threadIdx.x & 63) == 0) {
            wsum[threadIdx.x >> 6][0] = sx;
            wsum[threadIdx.x >> 6][1] = sy;
            wsum[threadIdx.x >> 6][2] = sz;
        }
        __syncthreads();
        if (threadIdx.x == 0) {
            float inv = 1.0f / (float)max(cnt, 1);
            mean[0] = (wsum[0][0] + wsum[1][0] + wsum[2][0] + wsum[3][0]) * inv;
            mean[1] = (wsum[0][1] + wsum[1][1] + wsum[2][1] + wsum[3][1]) * inv;
            mean[2] = (wsum[0][2] + wsum[1][2] + wsum[2][2] + wsum[3][2]) * inv;
        }
        __syncthreads();
        for (int n = lo + threadIdx.x; n < hi; n += 256) {
#pragma unroll
            for (int k = 0; k < 3; ++k) {
                float p = ldin(pos, n * 3 + k, f32o) - mean[k];
                ws[WS_POSC + n * 3 + k] = p;
                stout(out, f32o, O_CPRED + n * 3 + k, p);
                stout(out, f32o, O_CEPS + n * 3 + k, 0.0f);
            }
        }
        return;
    }

    const int t = blockIdx.x * blockDim.x + threadIdx.x;  // 640*256 = 163840
    const int f = dtype_f32(tt);
    if (t == 0) ws[WS_FLAG] = f ? 1.0f : 0.0f;
    if (t < 65536) {
        const int k = t >> 8, n = t & 255;
        ((unsigned short*)(ws + WT_AT))[n * 256 + k] = bbits(ldin(W_at, t, f));
        ((unsigned short*)(ws + WT_SH))[n * 256 + k] = bbits(ldin(W_shared, t, f));
        ((unsigned short*)(ws + WT_B0))[n * 256 + k] = bbits(ldin(W_b0, t, f));
    }
    if (t < 160000) ws[WS_X + t] = ldin(x, t, f);
    if (t < 8192) {
        const int k = t >> 5, n = t & 31;   // W_atoms (256,32)
        ((unsigned short*)(ws + WT_ATOMS))[n * 256 + k] = bbits(ldin(W_atoms, t, f));
    }
    if (t < 4096) {
        // W_b1 f16 B-fragments, CHAN-mapped: t = ts*512 + quad*128 + l16*8 + i
        const int i = t & 7, lc = (t >> 3) & 15, q = (t >> 7) & 3, ts = t >> 9;
        const int s = ts * 32 + q * 8 + i;          // storage channel
        float v = (lc < 10) ? ldin(W_b1, CHAN(s) * 10 + lc, f) : 0.0f;
        ((unsigned short*)(ws + WS_W1F))[t] = h16bits(v);
    }
    if (t < 4096) ws[WS_WATOM + t] = ldin(W_atom, t, f);
    if (t < 256) {
        ((unsigned short*)(ws + WS_WDH))[t] = h16bits(ldin(W_b0, 65536 + CHAN(t), f));
        ws[WS_BB0R + t] = ldin(b_b0, t, f);                // ORIGINAL order
        ws[WS_WTIME + t] = ldin(W_time, t, f);
        ws[WS_BTIME + t] = ldin(b_time, t, f);
        ws[WS_BATOM + t] = ldin(b_atom, t, f);
        ws[WS_BAT + t]   = ldin(b_at, t, f);
        ws[WS_BSH + t]   = ldin(b_shared, t, f);
    }
    if (t < 200) ws[WS_T + t] = ldin(tt, t, f);
    if (t < 32)  ws[WS_BATOMS + t] = ldin(b_atoms, t, f);
    if (t < 16)  ws[WS_BB1 + t] = (t < 10) ? ldin(b_b1, t, f) : 0.0f;
}

// ------- MFMA node pipeline + local-edge attrs (blocks >= NODE_BLOCKS) ----
__global__ __launch_bounds__(256) void k_node(
    const int* __restrict__ batch, const int* __restrict__ eil,
    const float* __restrict__ ws,
    unsigned int* __restrict__ h_out, void* __restrict__ out) {
    __shared__ unsigned short actA[16][APAD];
    __shared__ unsigned short actB[16][APAD];

    if (blockIdx.x >= NODE_BLOCKS) {
        // ---- local edges: 625 blocks x 256 threads == 160000 exact ----
        const int f32o = ws[WS_FLAG] != 0.0f;
        const int e = (blockIdx.x - NODE_BLOCKS) * 256 + threadIdx.x;
        const float* posc = ws + WS_POSC;
        const int s = eil[e];
        const int t = eil[EL_EDGES + e];
        float rx = posc[t * 3 + 0] - posc[s * 3 + 0];
        float ry = posc[t * 3 + 1] - posc[s * 3 + 1];
        float rz = posc[t * 3 + 2] - posc[s * 3 + 2];
        float dsq = rx * rx + ry * ry + rz * rz;
        float d = sqrtf(fmaxf(dsq, 1e-6f));
        float inv = 1.0f / d;
        stout(out, f32o, O_DL + e, d);
        stout(out, f32o, O_RNL + (size_t)e * 3 + 0, rx * inv);
        stout(out, f32o, O_RNL + (size_t)e * 3 + 1, ry * inv);
        stout(out, f32o, O_RNL + (size_t)e * 3 + 2, rz * inv);
        return;
    }

    const int tid = threadIdx.x;
    const int wave = tid >> 6, lane = tid & 63;
    const int quad = lane >> 4, l16 = lane & 15;
    const int row0 = blockIdx.x * 16;

    // ---- stage 0 (VALU f32): s0 = x@W_atom + b_atom + t[batch]*W_time + b_time
    {
        const int r = tid >> 4;
        const int c0 = (tid & 15) * 16;
        const int g = row0 + r;
        float tb = ws[WS_T + batch[g]];
        float xr[16];
#pragma unroll
        for (int k = 0; k < 16; ++k) xr[k] = ws[WS_X + g * 16 + k];
        for (int cc = 0; cc < 16; cc += 4) {
            const int c = c0 + cc;
            float a0 = ws[WS_BATOM + c + 0] + tb * ws[WS_WTIME + c + 0] + ws[WS_BTIME + c + 0];
            float a1 = ws[WS_BATOM + c + 1] + tb * ws[WS_WTIME + c + 1] + ws[WS_BTIME + c + 1];
            float a2 = ws[WS_BATOM + c + 2] + tb * ws[WS_WTIME + c + 2] + ws[WS_BTIME + c + 2];
            float a3 = ws[WS_BATOM + c + 3] + tb * ws[WS_WTIME + c + 3] + ws[WS_BTIME + c + 3];
#pragma unroll
            for (int k = 0; k < 16; ++k) {
                float4 w4 = *(const float4*)(ws + WS_WATOM + k * S_DIM + c);
                a0 += xr[k] * w4.x; a1 += xr[k] * w4.y;
                a2 += xr[k] * w4.z; a3 += xr[k] * w4.w;
            }
            actA[r][c + 0] = bbits(a0); actA[r][c + 1] = bbits(a1);
            actA[r][c + 2] = bbits(a2); actA[r][c + 3] = bbits(a3);
        }
    }
    __syncthreads();

    const unsigned short* wt_at = (const unsigned short*)(ws + WT_AT);
    const unsigned short* wt_sh = (const unsigned short*)(ws + WT_SH);
    const unsigned short* wt_b0 = (const unsigned short*)(ws + WT_B0);
    const unsigned short* wt_am = (const unsigned short*)(ws + WT_ATOMS);
    const int n0 = wave * 64;

    // ---- layer 1: actB = actA @ W_at + b_at
    {
        f32x4 acc[4] = {};
        for (int kk = 0; kk < S_DIM; kk += 32) {
            const int k = kk + quad * 8;
            bf16x8 a = *(const bf16x8*)&actA[l16][k];
#pragma unroll
            for (int nt = 0; nt < 4; ++nt) {
                bf16x8 b = *(const bf16x8*)(wt_at + (size_t)(n0 + nt * 16 + l16) * S_DIM + k);
                acc[nt] = __builtin_amdgcn_mfma_f32_16x16x32_bf16(a, b, acc[nt], 0, 0, 0);
            }
        }
#pragma unroll
        for (int nt = 0; nt < 4; ++nt) {
            const int n = n0 + nt * 16 + l16;
            const float bv = ws[WS_BAT + n];
#pragma unroll
            for (int r = 0; r < 4; ++r)
                actB[quad * 4 + r][n] = bbits(acc[nt][r] + bv);
        }
    }
    __syncthreads();

    // ---- layer 2: actA = silu(actB @ W_shared + b_shared)
    {
        f32x4 acc[4] = {};
        for (int kk = 0; kk < S_DIM; kk += 32) {
            const int k = kk + quad * 8;
            bf16x8 a = *(const bf16x8*)&actB[l16][k];
#pragma unroll
            for (int nt = 0; nt < 4; ++nt) {
                bf16x8 b = *(const bf16x8*)(wt_sh + (size_t)(n0 + nt * 16 + l16) * S_DIM + k);
                acc[nt] = __builtin_amdgcn_mfma_f32_16x16x32_bf16(a, b, acc[nt], 0, 0, 0);
            }
        }
        __syncthreads();
#pragma unroll
        for (int nt = 0; nt < 4; ++nt) {
            const int n = n0 + nt * 16 + l16;
            const float bv = ws[WS_BSH + n];
#pragma unroll
            for (int r = 0; r < 4; ++r)
                actA[quad * 4 + r][n] = bbits(silu(acc[nt][r] + bv));
        }
    }
    __syncthreads();

    // ---- layer 3: h = actA @ W_b0[:256] + 0.5*b_b0, fp8 e4m3 PERMUTED pack
    {
        f32x4 acc[4] = {};
        for (int kk = 0; kk < S_DIM; kk += 32) {
            const int k = kk + quad * 8;
            bf16x8 a = *(const bf16x8*)&actA[l16][k];
#pragma unroll
            for (int nt = 0; nt < 4; ++nt) {
                bf16x8 b = *(const bf16x8*)(wt_b0 + (size_t)(n0 + nt * 16 + l16) * S_DIM + k);
                acc[nt] = __builtin_amdgcn_mfma_f32_16x16x32_bf16(a, b, acc[nt], 0, 0, 0);
            }
        }
        float bh[4];
#pragma unroll
        for (int nt = 0; nt < 4; ++nt) bh[nt] = 0.5f * ws[WS_BB0R + n0 + nt * 16 + l16];
#pragma unroll
        for (int r = 0; r < 4; ++r) {
            const int g = row0 + quad * 4 + r;
            int w = 0;
            w = __builtin_amdgcn_cvt_pk_fp8_f32(acc[0][r] + bh[0], acc[1][r] + bh[1], w, false);
            w = __builtin_amdgcn_cvt_pk_fp8_f32(acc[2][r] + bh[2], acc[3][r] + bh[3], w, true);
            h_out[(size_t)g * 64 + wave * 16 + l16] = (unsigned int)w;
        }
    }

    // ---- layer 4: atoms = actA @ W_atoms + b_atoms (256 -> 32), waves 0,1
    if (wave < 2) {
        f32x4 acc = {};
        const int n = wave * 16 + l16;
        for (int kk = 0; kk < S_DIM; kk += 32) {
            const int k = kk + quad * 8;
            bf16x8 a = *(const bf16x8*)&actA[l16][k];
            bf16x8 b = *(const bf16x8*)(wt_am + (size_t)n * S_DIM + k);
            acc = __builtin_amdgcn_mfma_f32_16x16x32_bf16(a, b, acc, 0, 0, 0);
        }
        const float bv = ws[WS_BATOMS + n];
        const int f32o = ws[WS_FLAG] != 0.0f;
#pragma unroll
        for (int r = 0; r < 4; ++r) {
            const int g = row0 + quad * 4 + r;
            float v = acc[r] + bv;
            if (n < 16) stout(out, f32o, O_AEPS + (size_t)g * 16 + n, v);
            else        stout(out, f32o, O_APRED + (size_t)g * 16 + (n - 16), v);
        }
    }
}

// ---------------- bonds kernel: K-split pair, 16KB LDS -------------------
// 15625 blocks x 32 edges = 2 pairs x 16 edges. Each wave of a pair computes
// K-half sub*128..+128 (4 f16 MFMAs); stages 32 half-rows (128B) of fp8 h
// into a PRIVATE 4KB LDS region (barrier-free staging), XOR-swizzled
// (blk ^= row&7). One barrier for the cross-wave K-reduction.
union U8 { f16x8 v; f16x2 p[4]; };

__global__ __launch_bounds__(256, 8) void k_edges(const int* __restrict__ eig,
                                                  const float* __restrict__ ws,
                                                  const unsigned char* __restrict__ h,
                                                  void* __restrict__ out) {
    __shared__ __align__(16) unsigned char sm[4][32][128];   // 16 KB
    const int f32o = ws[WS_FLAG] != 0.0f;

    const int wave = threadIdx.x >> 6, lane = threadIdx.x & 63;
    const int quad = lane >> 4, l16 = lane & 15;
    const int P = wave >> 1, sub = wave & 1;
    const int e0 = blockIdx.x * 32 + P * 16;   // 15625*32 == 500000 exact
    unsigned char* smw = &sm[wave][0][0];

    // ---- stage 32 half-rows (128B): 4 passes x 8 rows, 16B/lane ----
    const int l8 = lane & 7, rg = lane >> 3;
#pragma unroll
    for (int p = 0; p < 4; ++p) {
        const int row = p * 8 + rg;                    // 0..31
        const int r16 = row & 15;
        const int es = e0 + r16;
        const int node = (row < 16) ? eig[EG_EDGES + es]   // rows 0-15: tgt i
                                    : eig[es];             // rows 16-31: src j
        uint4 v = *(const uint4*)(h + (size_t)node * 256 + sub * 128 + l8 * 16);
        *(uint4*)(smw + row * 128 + ((l8 ^ (row & 7)) << 4)) = v;
    }

    // ---- geometry: both subs compute d; sub0/quad0 writes outputs ----
    const int e = e0 + l16;
    const int j = eig[e];                // src
    const int i = eig[EG_EDGES + e];     // tgt
    const float* posc = ws + WS_POSC;
    float pix = posc[i * 3 + 0], piy = posc[i * 3 + 1], piz = posc[i * 3 + 2];
    float pjx = posc[j * 3 + 0], pjy = posc[j * 3 + 1], pjz = posc[j * 3 + 2];
    float rx = pix - pjx, ry = piy - pjy, rz = piz - pjz;
    float dsq = rx * rx + ry * ry + rz * rz;
    float dgeo = sqrtf(dsq);             // bonds d: no clip
    if (sub == 0 && quad == 0) {
        float ag = pix * pjx + piy * pjy + piz * pjz;
        float inv = 1.0f / sqrtf(fmaxf(dsq, 1e-6f));
        stout(out, f32o, O_AG + e, ag);
        stout(out, f32o, O_RNG + (size_t)e * 3 + 0, rx * inv);
        stout(out, f32o, O_RNG + (size_t)e * 3 + 1, ry * inv);
        stout(out, f32o, O_RNG + (size_t)e * 3 + 2, rz * inv);
    }

    const _Float16 hd = (_Float16)dgeo;
    const f16x2 d2h = {hd, hd};
    const unsigned short* wdh = (const unsigned short*)(ws + WS_WDH) + sub * 128;
    const _Float16* w1f = (const _Float16*)(ws + WS_W1F)
                        + (size_t)(sub * 4) * 512 + (quad * 16 + l16) * 8;
    const int rx7 = l16 & 7;
    const unsigned char* rowA = smw + l16 * 128;          // h_i half of edge l16
    const unsigned char* rowB = smw + (16 + l16) * 128;   // h_j half of edge l16

    f32x4 acc = {};
#pragma unroll
    for (int t = 0; t < 4; ++t) {
        // local k = t*32 + quad*8; 16B blk = 2t+(quad>>1), swizzled by rx7
        const int off = (((2 * t + (quad >> 1)) ^ rx7) << 4) + ((quad & 1) << 3);
        uint2 ua = *(const uint2*)(rowA + off);
        uint2 ub = *(const uint2*)(rowB + off);
        U8 W;  W.v = *(const f16x8*)(wdh + t * 32 + quad * 8);
        f16x8 WF = *(const f16x8*)(w1f + t * 512);
        f16x2 s0 = dec2<false>((int)ua.x) + dec2<false>((int)ub.x);
        f16x2 s1 = dec2<true>((int)ua.x)  + dec2<true>((int)ub.x);
        f16x2 s2 = dec2<false>((int)ua.y) + dec2<false>((int)ub.y);
        f16x2 s3 = dec2<true>((int)ua.y)  + dec2<true>((int)ub.y);
        U8 U;
        U.p[0] = hsilu2(s0 + d2h * W.p[0]);
        U.p[1] = hsilu2(s1 + d2h * W.p[1]);
        U.p[2] = hsilu2(s2 + d2h * W.p[2]);
        U.p[3] = hsilu2(s3 + d2h * W.p[3]);
        acc = __builtin_amdgcn_mfma_f32_16x16x32_f16(U.v, WF, acc, 0, 0, 0);
    }

    // ---- cross-wave K-reduction (sub1 -> sub0 via sub1's dead region) ----
    if (sub == 1) ((f32x4*)smw)[lane] = acc;
    __syncthreads();
    if (sub == 0 && l16 < 10) {
        f32x4 o = ((f32x4*)(smw + 4096))[lane];   // partner (sub1) region
        const float bv = ws[WS_BB1 + l16];
#pragma unroll
        for (int r = 0; r < 4; ++r) {
            const int er = e0 + quad * 4 + r;
            float v = acc[r] + o[r] + bv;
            if (l16 < 5) stout(out, f32o, O_BPRED + (size_t)er * 5 + l16, v);
            else         stout(out, f32o, O_BEPS + (size_t)er * 5 + (l16 - 5), v);
        }
    }
}

extern "C" void kernel_launch(void* const* d_in, const int* in_sizes, int n_in,
                              void* d_out, int out_size, void* d_ws, size_t ws_size,
                              hipStream_t stream) {
    const void* x        = d_in[0];
    const void* t        = d_in[1];
    const void* pos      = d_in[2];
    const int*  eil      = (const int*)d_in[3];
    const int*  eig      = (const int*)d_in[4];
    const int*  batch    = (const int*)d_in[6];
    const void* W_time   = d_in[7];
    const void* b_time   = d_in[8];
    const void* W_atom   = d_in[9];
    const void* b_atom   = d_in[10];
    const void* W_at     = d_in[11];
    const void* b_at     = d_in[12];
    const void* W_shared = d_in[13];
    const void* b_shared = d_in[14];
    const void* W_b0     = d_in[15];
    const void* b_b0     = d_in[16];
    const void* W_b1     = d_in[17];
    const void* b_b1     = d_in[18];
    const void* W_atoms  = d_in[20];
    const void* b_atoms  = d_in[21];
    (void)in_sizes; (void)n_in; (void)out_size;

    const size_t NEED = (size_t)WS_END_FLOATS * sizeof(float);
    if (ws_size < NEED) return;

    float* ws = (float*)d_ws;
    unsigned int* hbuf = (unsigned int*)(ws + WS_H);

    k_prep<<<PREP_BLOCKS + G_GRAPHS, 256, 0, stream>>>(
        x, t, W_time, b_time, W_atom, b_atom, W_at, b_at, W_shared, b_shared,
        W_b0, b_b0, W_b1, b_b1, W_atoms, b_atoms, pos, batch, ws, d_out);
    k_node<<<NODE_BLOCKS + LOCAL_BLOCKS, 256, 0, stream>>>(
        batch, eil, ws, hbuf, d_out);
    k_edges<<<BONDS3, 256, 0, stream>>>(
        eig, ws, (const unsigned char*)hbuf, d_out);
}